// Round 5
// baseline (2285.385 us; speedup 1.0000x reference)
//
#include <hip/hip_runtime.h>
#include <math.h>

// Problem constants
#define NV 32000
#define ND 300
#define NH 300
#define NK 9
#define NB 64
#define NT 512

typedef short bf16x8 __attribute__((ext_vector_type(8)));
typedef float f32x4  __attribute__((ext_vector_type(4)));

__device__ inline short bf16r(float x) {
    return (short)((__float_as_uint(x) + 0x8000u) >> 16);
}

__device__ inline float tanh_fast(float x) {
    float e2 = __expf(2.f * x);
    return 1.f - 2.f / (e2 + 1.f);
}

// LDS-only barrier (no vmcnt drain).
__device__ inline void bar_lds() {
    asm volatile("s_waitcnt lgkmcnt(0)" ::: "memory");
    __builtin_amdgcn_s_barrier();
    asm volatile("" ::: "memory");
}

// ---------------- workspace layout (float offsets) ----------------
#define WB_OFF   0ull
#define WB_F     768000ull                // 1,536,000 shorts = 768,000 floats
#define E_OFF    (WB_OFF + WB_F)
#define E_SZ     ((unsigned long long)NT*NB*NK)          // 294,912
#define CBUF_OFF (E_OFF + E_SZ)
#define CBUF_SZ  (2ull*NB*NH)             // 38,400
#define HSLOT_OFF (CBUF_OFF + CBUF_SZ)
#define HSLOT_SZ  (2ull*2*NB*NH)          // 76,800
#define XP_OFF   (HSLOT_OFF + HSLOT_SZ)   // 1,178,112
// 32-step chunk: [dir][sp32][gb8][sl15][bl8][80]; two buffers
#define XPC32_SZ (2ull*32*1200*64)        // 4,915,200 floats per buffer

// =====================================================================
// K0: convert W_ih AND W_hh (fwd+bwd) to bf16, zero-padded K 300->320.
// =====================================================================
__global__ __launch_bounds__(256) void k_wcvt(
    const float* __restrict__ wihf, const float* __restrict__ wihb,
    const float* __restrict__ whhf, const float* __restrict__ whhb,
    short* __restrict__ dst)
{
    int i = blockIdx.x*256 + threadIdx.x;          // over 4*1200*320
    if (i >= 1536000) return;
    int d  = i / 384000;
    int r2 = i % 384000;
    int j  = r2 / 320, k = r2 % 320;
    const float* src = (d == 0) ? wihf : (d == 1) ? wihb : (d == 2) ? whhf : whhb;
    float v = (k < 300) ? src[(size_t)j*300 + k] : 0.f;
    dst[i] = bf16r(v);
}

// =====================================================================
// K_FUSED: blocks [0,80) = rnn (5 shards of 60 units, chunk c, 32 steps);
//          blocks [80, 80+480) = xproj chunk c+1 (unchanged, verified).
//   Shard width 20->60: rendezvous width per (dir,gb) group 15->5 WGs.
//   A-fragments 240 gate rows -> 160 VGPR/thread; ks-outer MFMA loop
//   keeps one Bf live + acc[4] interleaved (4-way ILP, low pressure).
//   Exchange protocol (tagged u32 via LLC) byte-identical to verified.
// =====================================================================
__global__ __launch_bounds__(256) void k_fused(
    const int* __restrict__ tokens, const float* __restrict__ emb,
    const short* __restrict__ wb16,
    const float* __restrict__ bif, const float* __restrict__ bhf,
    const float* __restrict__ bib, const float* __restrict__ bhb,
    float* __restrict__ xp_dst, int chunk_next,
    const float* __restrict__ xp_src,
    const short* __restrict__ whh16,
    const float* __restrict__ h0,
    unsigned* hslot, float* __restrict__ cbuf,
    float* __restrict__ ev, const float* __restrict__ wout,
    int s_begin, int do_rnn)
{
    __shared__ __align__(16) short h_sh16[16*328];   // [b16][k328] bf16
    __shared__ __align__(16) float xp_sh[1920];      // 3 x [bl8][80]
    __shared__ __align__(16) float gates_sh[240*9];  // [r240][b8] pad 9
    __shared__ __align__(16) float wo_sh[540];       // [k9][u60]
    __shared__ __align__(16) float hloc[480];        // [b8][u60]
    __shared__ __align__(16) float ev_loc[32*72];    // per-32-step window

    const int tid = threadIdx.x;
    const int nrnn = do_rnn ? 80 : 0;

    if ((int)blockIdx.x < nrnn) {
        // ================= RNN branch =================
        const int wv  = tid >> 6, L = tid & 63;
        const int lm  = L & 15, lq = L >> 4;
        const int dir = blockIdx.x / 40;
        const int rem = blockIdx.x % 40;
        const int sl  = rem / 8;           // 0..4
        const int gb  = rem % 8;
        const int u0  = sl * 60;

        const int tn = (wv == 3) ? 3 : 4;  // m-tiles per wave (15 total)

        // ---- register-resident Whh a-fragments (bf16): 240 rows ----
        bf16x8 A[4][10];
#pragma unroll
        for (int mt = 0; mt < 4; ++mt) {
            if (mt < tn) {
                int r = (wv*4 + mt)*16 + lm;              // local row 0..239
                int grow = (r/60)*300 + u0 + (r%60);      // global gate row
                const short* wr = whh16 + ((size_t)dir*1200 + grow)*320;
#pragma unroll
                for (int ks = 0; ks < 10; ++ks)
                    A[mt][ks] = *(const bf16x8*)(wr + ks*32 + lq*8);
            }
        }
        for (int i = tid; i < 540; i += 256)
            wo_sh[i] = wout[(i/60)*600 + dir*300 + u0 + (i%60)];

        for (int i = tid; i < 16*328; i += 256) h_sh16[i] = 0;

        // ---- cell state: 480 cells over 256 threads (2 reps) ----
        const int bl0 = tid/60,      lu0 = tid%60;
        const int bl1 = (tid+256)/60, lu1 = (tid+256)%60;
        const bool r1v = (tid < 224);
        float c0r = cbuf[((size_t)dir*NB + gb*8 + bl0)*NH + u0 + lu0];
        float c1r = 0.f;
        if (r1v) c1r = cbuf[((size_t)dir*NB + gb*8 + bl1)*NH + u0 + lu1];

        // ---- xp prefetch (3 x 20-unit sub-slices) ----
        auto xaddr = [&](int s, int slc) -> const float* {
            int sp = s - s_begin;
            return xp_src + ((((size_t)dir*32 + sp)*8 + gb)*15 + (sl*3 + slc))*640
                          + (size_t)tid*4;
        };
        float4 xpr0, xpr1, xpr2;
        if (tid < 160) {
            xpr0 = *(const float4*)xaddr(s_begin, 0);
            xpr1 = *(const float4*)xaddr(s_begin, 1);
            xpr2 = *(const float4*)xaddr(s_begin, 2);
        }

        bar_lds();

        for (int s = s_begin; s < s_begin + 32; ++s) {
            // ---- speculative tagged loads of h^(s) ----
            unsigned vb[10];
            unsigned* hsrc = hslot + (((size_t)(s & 1)*2 + dir)*NB + gb*8)*NH;
            if (s > 0 && tid < 240) {
#pragma unroll
                for (int j = 0; j < 10; ++j) {
                    int i = tid + 256*j;
                    if (i < 2400)
                        vb[j] = __hip_atomic_load(hsrc + i, __ATOMIC_RELAXED,
                                                  __HIP_MEMORY_SCOPE_AGENT);
                }
            }

            // ---- stage xp from prefetched regs; prefetch next ----
            if (tid < 160) {
                *(float4*)(&xp_sh[tid*4])        = xpr0;
                *(float4*)(&xp_sh[640 + tid*4])  = xpr1;
                *(float4*)(&xp_sh[1280 + tid*4]) = xpr2;
                if ((s + 1) < s_begin + 32) {
                    xpr0 = *(const float4*)xaddr(s + 1, 0);
                    xpr1 = *(const float4*)xaddr(s + 1, 1);
                    xpr2 = *(const float4*)xaddr(s + 1, 2);
                }
            }

            // ---- verify tags, scatter bf16 payload -> h_sh ----
            if (s == 0) {
                const float* h0p = h0 + ((size_t)dir*NB + gb*8)*NH;
                for (int i = tid; i < 2400; i += 256)
                    h_sh16[(i/300)*328 + (i%300)] = bf16r(h0p[i]);
            } else if (tid < 240) {
                const unsigned tg = (unsigned)s & 0xFFFFu;
                bool ok = false;
                while (!ok) {
                    ok = true;
#pragma unroll
                    for (int j = 0; j < 10; ++j) {
                        int i = tid + 256*j;
                        if (i < 2400 && (vb[j] >> 16) != tg) {
                            ok = false;
                            vb[j] = __hip_atomic_load(hsrc + i, __ATOMIC_RELAXED,
                                                      __HIP_MEMORY_SCOPE_AGENT);
                        }
                    }
                }
#pragma unroll
                for (int j = 0; j < 10; ++j) {
                    int i = tid + 256*j;
                    if (i < 2400)
                        h_sh16[(i/300)*328 + (i%300)] = (short)(vb[j] & 0xFFFFu);
                }
            }
            bar_lds();                                     // B1: h ready

            // ---- MFMA: gates[240x8] = Whh * h, ks-outer, acc[4] ILP ----
            {
                f32x4 acc[4];
#pragma unroll
                for (int mt = 0; mt < 4; ++mt)
#pragma unroll
                    for (int r = 0; r < 4; ++r) acc[mt][r] = 0.f;

                bf16x8 bcur = *(const bf16x8*)(h_sh16 + lm*328 + lq*8);
#pragma unroll
                for (int ks = 0; ks < 10; ++ks) {
                    bf16x8 bn;
                    if (ks < 9)
                        bn = *(const bf16x8*)(h_sh16 + lm*328 + (ks+1)*32 + lq*8);
#pragma unroll
                    for (int mt = 0; mt < 4; ++mt)
                        if (mt < tn)
                            acc[mt] = __builtin_amdgcn_mfma_f32_16x16x32_bf16(
                                          A[mt][ks], bcur, acc[mt], 0, 0, 0);
                    bcur = bn;
                }
                if (lm < 8) {
#pragma unroll
                    for (int mt = 0; mt < 4; ++mt)
                        if (mt < tn) {
#pragma unroll
                            for (int r = 0; r < 4; ++r)
                                gates_sh[((wv*4+mt)*16 + lq*4 + r)*9 + lm] = acc[mt][r];
                        }
                }
            }
            bar_lds();                                     // B2: gates ready

            // ---- pointwise LSTM cell + tagged publish (2 reps) ----
            {
                // rep 0: cell index tid
                int slc = lu0/20, ul = lu0%20;
                float G0 = xp_sh[slc*640 + bl0*80 +      ul] + gates_sh[(      lu0)*9 + bl0];
                float G1 = xp_sh[slc*640 + bl0*80 + 20 + ul] + gates_sh[( 60 + lu0)*9 + bl0];
                float G2 = xp_sh[slc*640 + bl0*80 + 40 + ul] + gates_sh[(120 + lu0)*9 + bl0];
                float G3 = xp_sh[slc*640 + bl0*80 + 60 + ul] + gates_sh[(180 + lu0)*9 + bl0];
                float ig = 1.f/(1.f+__expf(-G0));
                float fg = 1.f/(1.f+__expf(-G1));
                float gg = tanh_fast(G2);
                float og = 1.f/(1.f+__expf(-G3));
                c0r = fg*c0r + ig*gg;
                float h = og*tanh_fast(c0r);
                unsigned hb = (__float_as_uint(h) + 0x8000u) >> 16;
                unsigned pk = (((unsigned)(s+1) & 0xFFFFu) << 16) | hb;
                __hip_atomic_store(
                    &hslot[(((size_t)((s+1)&1)*2 + dir)*NB + gb*8 + bl0)*NH + u0 + lu0],
                    pk, __ATOMIC_RELAXED, __HIP_MEMORY_SCOPE_AGENT);
                hloc[bl0*60 + lu0] = h;
            }
            if (r1v) {
                // rep 1: cell index tid+256
                int slc = lu1/20, ul = lu1%20;
                float G0 = xp_sh[slc*640 + bl1*80 +      ul] + gates_sh[(      lu1)*9 + bl1];
                float G1 = xp_sh[slc*640 + bl1*80 + 20 + ul] + gates_sh[( 60 + lu1)*9 + bl1];
                float G2 = xp_sh[slc*640 + bl1*80 + 40 + ul] + gates_sh[(120 + lu1)*9 + bl1];
                float G3 = xp_sh[slc*640 + bl1*80 + 60 + ul] + gates_sh[(180 + lu1)*9 + bl1];
                float ig = 1.f/(1.f+__expf(-G0));
                float fg = 1.f/(1.f+__expf(-G1));
                float gg = tanh_fast(G2);
                float og = 1.f/(1.f+__expf(-G3));
                c1r = fg*c1r + ig*gg;
                float h = og*tanh_fast(c1r);
                unsigned hb = (__float_as_uint(h) + 0x8000u) >> 16;
                unsigned pk = (((unsigned)(s+1) & 0xFFFFu) << 16) | hb;
                __hip_atomic_store(
                    &hslot[(((size_t)((s+1)&1)*2 + dir)*NB + gb*8 + bl1)*NH + u0 + lu1],
                    pk, __ATOMIC_RELAXED, __HIP_MEMORY_SCOPE_AGENT);
                hloc[bl1*60 + lu1] = h;
            }
            bar_lds();                                     // B3: hloc ready

            // ---- emission -> LDS window ----
            const int widx = (s - s_begin) & 31;
            if (tid < 72) {
                int b = tid/9, k = tid%9;
                float a = 0.f;
#pragma unroll
                for (int u = 0; u < 60; ++u) a += hloc[b*60+u]*wo_sh[k*60+u];
                ev_loc[widx*72 + tid] = a;
            }

            // ---- bulk flush once per 32 steps ----
            if (widx == 31) {
                bar_lds();
                const int sbase = s - 31;
                for (int i = tid; i < 32*72; i += 256) {
                    int wi = i / 72, j = i % 72;
                    int bb = j / 9, kk = j % 9;
                    int tt = dir ? (511 - (sbase + wi)) : (sbase + wi);
                    atomicAdd(&ev[((size_t)tt*NB + gb*8 + bb)*NK + kk], ev_loc[i]);
                }
            }
        }

        cbuf[((size_t)dir*NB + gb*8 + bl0)*NH + u0 + lu0] = c0r;
        if (r1v) cbuf[((size_t)dir*NB + gb*8 + bl1)*NH + u0 + lu1] = c1r;

    } else {
        // ================= XPROJ branch (32-step chunk, unchanged) =======
        const int bx = (int)blockIdx.x - nrnn;       // [0, 480)
        const int w  = tid >> 6, L = tid & 63;
        const int lm = L & 15, lq = L >> 4;
        const int xb = bx & 15;                      // 16 m-blocks
        const int yb = (bx >> 4) % 15;               // 15 n-blocks
        const int dir = bx / 240;                    // 2 dirs
        const int m0 = xb*128 + w*32;
        const int n0 = yb*80;
        const int tbase = dir ? (480 - chunk_next*32) : (chunk_next*32);

        const float* arow[2];
#pragma unroll
        for (int mi = 0; mi < 2; ++mi) {
            int m = m0 + mi*16 + lm;
            int b = m >> 5, lt = m & 31;
            arow[mi] = emb + (size_t)tokens[b*512 + tbase + lt] * 300;
        }
        const short* brow[5];
#pragma unroll
        for (int ni = 0; ni < 5; ++ni) {
            int j = n0 + ni*16 + lm;
            brow[ni] = wb16 + ((size_t)dir*1200 + j)*320;
        }

        f32x4 acc[2][5];
#pragma unroll
        for (int mi = 0; mi < 2; ++mi)
#pragma unroll
            for (int ni = 0; ni < 5; ++ni)
#pragma unroll
                for (int r = 0; r < 4; ++r) acc[mi][ni][r] = 0.f;

        const float4 z4 = make_float4(0.f,0.f,0.f,0.f);
        for (int k0 = 0; k0 < 320; k0 += 32) {
            const int kk = k0 + lq*8;
            bf16x8 af[2], bf[5];
#pragma unroll
            for (int mi = 0; mi < 2; ++mi) {
                float4 f1 = (kk   < 300) ? *(const float4*)(arow[mi] + kk)     : z4;
                float4 f2 = (kk+4 < 300) ? *(const float4*)(arow[mi] + kk + 4) : z4;
                af[mi][0]=bf16r(f1.x); af[mi][1]=bf16r(f1.y); af[mi][2]=bf16r(f1.z); af[mi][3]=bf16r(f1.w);
                af[mi][4]=bf16r(f2.x); af[mi][5]=bf16r(f2.y); af[mi][6]=bf16r(f2.z); af[mi][7]=bf16r(f2.w);
            }
#pragma unroll
            for (int ni = 0; ni < 5; ++ni)
                bf[ni] = *(const bf16x8*)(brow[ni] + kk);
#pragma unroll
            for (int mi = 0; mi < 2; ++mi)
#pragma unroll
                for (int ni = 0; ni < 5; ++ni)
                    acc[mi][ni] = __builtin_amdgcn_mfma_f32_16x16x32_bf16(
                                      af[mi], bf[ni], acc[mi][ni], 0, 0, 0);
        }

#pragma unroll
        for (int ni = 0; ni < 5; ++ni) {
            int j = n0 + ni*16 + lm;
            int g = j/300, rr = j%300;
            int slc = rr/20, ul = rr%20;
            float bias = dir ? (bib[j]+bhb[j]) : (bif[j]+bhf[j]);
#pragma unroll
            for (int mi = 0; mi < 2; ++mi) {
#pragma unroll
                for (int r = 0; r < 4; ++r) {
                    int m = m0 + mi*16 + lq*4 + r;
                    int b = m >> 5, lt = m & 31;
                    int sp = dir ? (31 - lt) : lt;
                    size_t idx = ((((size_t)dir*32 + sp)*8 + (b>>3))*15 + slc)*640
                               + (size_t)(b&7)*80 + g*20 + ul;
                    xp_dst[idx] = acc[mi][ni][r] + bias;
                }
            }
        }
    }
}

// =====================================================================
// K3: CRF nll + viterbi — two-wave split scan + parallel backtrack
//   (unchanged — verified, 162us).
// =====================================================================
#define BT_C 14
#define BT_L 37

__global__ __launch_bounds__(128) void k_crf(
    const float* __restrict__ ev, const int* __restrict__ tags,
    const float* __restrict__ start_t, const float* __restrict__ end_t,
    const float* __restrict__ trans, const float* __restrict__ bout,
    float* __restrict__ out)
{
    __shared__ __align__(16) float ex_a[12];
    __shared__ __align__(16) float ex_v[12];
    __shared__ int hist_sh[511*NK];
    __shared__ int fmap[BT_C*NK];
    __shared__ int entry_sh[BT_C];
    __shared__ int last_sh;

    const int b = blockIdx.x, tid = threadIdx.x;
    const int wv = tid >> 6, ln = tid & 63;

    if (wv == 0) {
        float part = 0.f;
        for (int t = ln; t < NT; t += 64) {
            int tc = tags[b*NT + t];
            float e = ev[((size_t)t*NB + b)*NK + tc] + bout[tc];
            float pre = (t == 0) ? start_t[tc] : trans[tags[b*NT + t - 1]*9 + tc];
            part += pre + e;
        }
        if (ln == 63) part += end_t[tags[b*NT + NT - 1]];
#pragma unroll
        for (int off = 32; off > 0; off >>= 1)
            part += __shfl_down(part, off, 64);
        const float num = part;   // lane 0

        if (ln < 9) {
            const int kc = ln;
            float Tc[9];
#pragma unroll
            for (int kp = 0; kp < 9; ++kp) Tc[kp] = __expf(trans[kp*9 + kc]);
            const float bo = bout[kc];
            ex_a[kc] = start_t[kc] + ev[(size_t)b*NK + kc] + bo;
            float etn = ev[((size_t)1*NB + b)*NK + kc] + bo;

            for (int t = 1; t < NT; ++t) {
                float et = etn;
                if (t + 1 < NT) etn = ev[((size_t)(t+1)*NB + b)*NK + kc] + bo;

                float4 s0 = *(const float4*)(&ex_a[0]);
                float4 s1 = *(const float4*)(&ex_a[4]);
                float  a8 = ex_a[8];
                float a0=s0.x,a1=s0.y,a2=s0.z,a3=s0.w,a4=s1.x,a5=s1.y,a6=s1.z,a7=s1.w;

                float M = fmaxf(fmaxf(fmaxf(a0,a1),fmaxf(a2,a3)),
                                fmaxf(fmaxf(a4,a5),fmaxf(a6,a7)));
                M = fmaxf(M, a8);
                float s =        __expf(a0-M)*Tc[0];
                s = fmaf(__expf(a1-M), Tc[1], s);
                s = fmaf(__expf(a2-M), Tc[2], s);
                s = fmaf(__expf(a3-M), Tc[3], s);
                s = fmaf(__expf(a4-M), Tc[4], s);
                s = fmaf(__expf(a5-M), Tc[5], s);
                s = fmaf(__expf(a6-M), Tc[6], s);
                s = fmaf(__expf(a7-M), Tc[7], s);
                s = fmaf(__expf(a8-M), Tc[8], s);
                ex_a[kc] = M + __logf(s) + et;
            }

            if (ln == 0) {
                float M = -1e30f;
#pragma unroll
                for (int k = 0; k < 9; ++k) M = fmaxf(M, ex_a[k] + end_t[k]);
                float ls = 0.f;
#pragma unroll
                for (int k = 0; k < 9; ++k) ls += __expf(ex_a[k] + end_t[k] - M);
                float den = M + __logf(ls);
                atomicAdd(out + NB*NT, den - num);
            }
        }
    } else {
        if (ln < 9) {
            const int kc = ln;
            float Tc[9];
#pragma unroll
            for (int kp = 0; kp < 9; ++kp) Tc[kp] = trans[kp*9 + kc];
            const float bo = bout[kc];
            ex_v[kc] = start_t[kc] + ev[(size_t)b*NK + kc] + bo;
            float etn = ev[((size_t)1*NB + b)*NK + kc] + bo;

            for (int t = 1; t < NT; ++t) {
                float et = etn;
                if (t + 1 < NT) etn = ev[((size_t)(t+1)*NB + b)*NK + kc] + bo;

                float4 s0 = *(const float4*)(&ex_v[0]);
                float4 s1 = *(const float4*)(&ex_v[4]);
                float  a8 = ex_v[8];
                float a0=s0.x,a1=s0.y,a2=s0.z,a3=s0.w,a4=s1.x,a5=s1.y,a6=s1.z,a7=s1.w;

                float bv = a0 + Tc[0]; int arg = 0;
                float v;
                v = a1+Tc[1]; if (v > bv) { bv = v; arg = 1; }
                v = a2+Tc[2]; if (v > bv) { bv = v; arg = 2; }
                v = a3+Tc[3]; if (v > bv) { bv = v; arg = 3; }
                v = a4+Tc[4]; if (v > bv) { bv = v; arg = 4; }
                v = a5+Tc[5]; if (v > bv) { bv = v; arg = 5; }
                v = a6+Tc[6]; if (v > bv) { bv = v; arg = 6; }
                v = a7+Tc[7]; if (v > bv) { bv = v; arg = 7; }
                v = a8+Tc[8]; if (v > bv) { bv = v; arg = 8; }
                hist_sh[(t-1)*NK + kc] = arg;
                ex_v[kc] = bv + et;
            }

            if (ln == 0) {
                float best = -1e30f; int last = 0;
#pragma unroll
                for (int k = 0; k < 9; ++k) {
                    float v = ex_v[k] + end_t[k];
                    if (v > best) { best = v; last = k; }
                }
                last_sh = last;
            }
        }
    }

    __syncthreads();

    if (tid < BT_C*NK) {
        int c = tid / NK, s = tid % NK;
        int lo = c*BT_L, hi = min(511, lo + BT_L);
        int pos = s;
        for (int i = hi - 1; i >= lo; --i) pos = hist_sh[i*NK + pos];
        fmap[c*NK + s] = pos;
    }
    __syncthreads();
    if (tid == 0) {
        int e = last_sh;
        entry_sh[BT_C-1] = e;
        for (int c = BT_C - 2; c >= 0; --c) {
            e = fmap[(c+1)*NK + e];
            entry_sh[c] = e;
        }
    }
    __syncthreads();
    int* pout = (int*)out;
    if (tid < BT_C) {
        int c = tid;
        int lo = c*BT_L, hi = min(511, lo + BT_L);
        int pos = entry_sh[c];
        for (int i = hi - 1; i >= lo; --i) {
            pos = hist_sh[i*NK + pos];
            pout[b*NT + i] = pos;
        }
    }
    if (tid == 0) pout[b*NT + NT - 1] = last_sh;
}

// =====================================================================
extern "C" void kernel_launch(void* const* d_in, const int* in_sizes, int n_in,
                              void* d_out, int out_size, void* d_ws, size_t ws_size,
                              hipStream_t stream)
{
    (void)in_sizes; (void)n_in; (void)ws_size;

    const int*   tokens = (const int*)  d_in[0];
    const int*   tags   = (const int*)  d_in[1];
    const float* emb    = (const float*)d_in[3];
    const float* wihf   = (const float*)d_in[4];
    const float* whhf   = (const float*)d_in[5];
    const float* bihf   = (const float*)d_in[6];
    const float* bhhf   = (const float*)d_in[7];
    const float* wihb   = (const float*)d_in[8];
    const float* whhb   = (const float*)d_in[9];
    const float* bib    = (const float*)d_in[10];
    const float* bhhb   = (const float*)d_in[11];
    const float* h0     = (const float*)d_in[12];
    const float* c0     = (const float*)d_in[13];
    const float* wout   = (const float*)d_in[14];
    const float* bout   = (const float*)d_in[15];
    const float* startt = (const float*)d_in[16];
    const float* endt   = (const float*)d_in[17];
    const float* trans  = (const float*)d_in[18];

    float* ws    = (float*)d_ws;
    short* wb16  = (short*)(ws + WB_OFF);
    short* whh16 = wb16 + 768000;
    float* evp   = ws + E_OFF;
    float* cbuf  = ws + CBUF_OFF;
    unsigned* hslot = (unsigned*)(ws + HSLOT_OFF);
    float* xp    = ws + XP_OFF;          // two XPC32 buffers
    float* out   = (float*)d_out;

    (void)hipMemsetAsync(d_out, 0, (size_t)out_size * sizeof(float), stream);
    (void)hipMemsetAsync(evp, 0, (size_t)E_SZ * sizeof(float), stream);
    // hslot needs NO init: stale tags never match the wanted in-run tag.
    (void)hipMemcpyAsync(cbuf, c0, 2ull*NB*NH*sizeof(float), hipMemcpyDeviceToDevice, stream);

    k_wcvt<<<6000, 256, 0, stream>>>(wihf, wihb, whhf, whhb, wb16);

    // chunk 0 xproj alone (480 WGs, do_rnn=0)
    k_fused<<<480, 256, 0, stream>>>(
        tokens, emb, wb16, bihf, bhhf, bib, bhhb,
        xp, 0,
        xp, whh16, h0, hslot, cbuf, evp, wout, 0, 0);

    // fused: rnn(chunk c) + xproj(chunk c+1)
    for (int c = 0; c < 15; ++c) {
        k_fused<<<560, 256, 0, stream>>>(
            tokens, emb, wb16, bihf, bhhf, bib, bhhb,
            xp + (size_t)((c+1)&1)*XPC32_SZ, c+1,
            xp + (size_t)(c&1)*XPC32_SZ, whh16, h0, hslot, cbuf, evp, wout,
            32*c, 1);
    }
    // final chunk: rnn only
    k_fused<<<80, 256, 0, stream>>>(
        tokens, emb, wb16, bihf, bhhf, bib, bhhb,
        xp, 0,
        xp + (size_t)XPC32_SZ, whh16, h0, hslot, cbuf, evp, wout,
        480, 1);

    k_crf<<<64, 128, 0, stream>>>(evp, tags, startt, endt, trans, bout, out);
}

// Round 9
// 2011.565 us; speedup vs baseline: 1.1361x; 1.1361x over previous
//
#include <hip/hip_runtime.h>
#include <math.h>

// Problem constants
#define NV 32000
#define ND 300
#define NH 300
#define NK 9
#define NB 64
#define NT 512

typedef short bf16x8 __attribute__((ext_vector_type(8)));
typedef float f32x4  __attribute__((ext_vector_type(4)));

__device__ inline short bf16r(float x) {
    return (short)((__float_as_uint(x) + 0x8000u) >> 16);
}

__device__ inline float tanh_fast(float x) {
    float e2 = __expf(2.f * x);
    return 1.f - 2.f / (e2 + 1.f);
}

// ---------------- workspace layout (float offsets) ----------------
#define WB_OFF   0ull
#define WB_F     768000ull                // 1,536,000 shorts = 768,000 floats
#define E_OFF    (WB_OFF + WB_F)
#define E_SZ     ((unsigned long long)NT*NB*NK)          // 294,912
#define CBUF_OFF (E_OFF + E_SZ)
#define CBUF_SZ  (2ull*NB*NH)             // 38,400
#define HSLOT_OFF (CBUF_OFF + CBUF_SZ)
#define HSLOT_SZ  (2ull*2*NB*NH)          // 76,800
#define XP_OFF   (HSLOT_OFF + HSLOT_SZ)   // 1,178,112
// 32-step chunk: [dir][sp32][gb8][sl15][bl8][80]; two buffers
#define XPC32_SZ (2ull*32*1200*64)        // 4,915,200 floats per buffer

// =====================================================================
// K0: convert W_ih AND W_hh (fwd+bwd) to bf16, zero-padded K 300->320.
// =====================================================================
__global__ __launch_bounds__(256) void k_wcvt(
    const float* __restrict__ wihf, const float* __restrict__ wihb,
    const float* __restrict__ whhf, const float* __restrict__ whhb,
    short* __restrict__ dst)
{
    int i = blockIdx.x*256 + threadIdx.x;          // over 4*1200*320
    if (i >= 1536000) return;
    int d  = i / 384000;
    int r2 = i % 384000;
    int j  = r2 / 320, k = r2 % 320;
    const float* src = (d == 0) ? wihf : (d == 1) ? wihb : (d == 2) ? whhf : whhb;
    float v = (k < 300) ? src[(size_t)j*300 + k] : 0.f;
    dst[i] = bf16r(v);
}

// =====================================================================
// K_FUSED: blocks [0,240) = rnn (20-unit shards, chunk c, 32 steps);
//          blocks [240, 240+480) = xproj chunk c+1.
//   RNN step body = round-1's verified best-measured structure:
//   __syncthreads barriers (standard, full drain — measured 2.49us/step
//   vs 2.83 for all bar_lds variants), per-step fire-and-forget
//   emission atomics, no LDS emission window (LDS ~18KB).
// =====================================================================
__global__ __launch_bounds__(256) void k_fused(
    const int* __restrict__ tokens, const float* __restrict__ emb,
    const short* __restrict__ wb16,
    const float* __restrict__ bif, const float* __restrict__ bhf,
    const float* __restrict__ bib, const float* __restrict__ bhb,
    float* __restrict__ xp_dst, int chunk_next,
    const float* __restrict__ xp_src,
    const short* __restrict__ whh16,
    const float* __restrict__ h0,
    unsigned* hslot, float* __restrict__ cbuf,
    float* __restrict__ ev, const float* __restrict__ wout,
    int s_begin, int do_rnn)
{
    __shared__ __align__(16) short h_sh16[16*328];   // [b16][k328] bf16
    __shared__ __align__(16) float xp_sh[640];
    __shared__ __align__(16) float gates_sh[80*9];   // [r80][b8] pad 9
    __shared__ __align__(16) float wo_sh[180];
    __shared__ __align__(16) float hloc[160];

    const int tid = threadIdx.x;
    const int nrnn = do_rnn ? 240 : 0;

    if ((int)blockIdx.x < nrnn) {
        // ================= RNN branch (r1-verified step body) ============
        const int wv  = tid >> 6, L = tid & 63;
        const int lm  = L & 15, lq = L >> 4;
        const int dir = blockIdx.x / 120;
        const int rem = blockIdx.x % 120;
        const int sl  = rem / 8;
        const int gb  = rem % 8;
        const int u0  = sl * 20;

        const int tb = (wv == 0) ? 0 : (wv + 1);
        const int tn = (wv == 0) ? 2 : 1;

        bf16x8 A[2][10];
#pragma unroll 2
        for (int mt = 0; mt < 2; ++mt) {
            if (mt < tn) {
                int r = (tb + mt)*16 + lm;
                int grow = (r/20)*300 + u0 + (r%20);
                const short* wr = whh16 + ((size_t)dir*1200 + grow)*320;
#pragma unroll
                for (int ks = 0; ks < 10; ++ks)
                    A[mt][ks] = *(const bf16x8*)(wr + ks*32 + lq*8);
            }
        }
        if (tid < 180) wo_sh[tid] = wout[(tid/20)*600 + dir*300 + u0 + (tid%20)];

        for (int i = tid; i < 16*328; i += 256) h_sh16[i] = 0;

        const bool isPW = (tid < 160);
        const int bl_p = tid/20, lu_p = tid%20;
        float c_reg = 0.f;
        if (isPW) c_reg = cbuf[((size_t)dir*NB + gb*8 + bl_p)*NH + u0 + lu_p];

        __syncthreads();

        for (int s = s_begin; s < s_begin + 32; ++s) {
            const int t = dir ? (511 - s) : s;
            const int sp = s - s_begin;

            // ---- speculative tagged loads of h^(s) (one L3 trip) ----
            unsigned vb[10];
            unsigned* hsrc = hslot + (((size_t)(s & 1)*2 + dir)*NB + gb*8)*NH;
            if (s > 0 && tid < 240) {
#pragma unroll
                for (int j = 0; j < 10; ++j) {
                    int i = tid + 256*j;
                    if (i < 2400)
                        vb[j] = __hip_atomic_load(hsrc + i, __ATOMIC_RELAXED,
                                                  __HIP_MEMORY_SCOPE_AGENT);
                }
            }

            // ---- stage xp (h-independent; overlaps spec loads) ----
            {
                const float* xsrc = xp_src
                    + ((((size_t)dir*32 + sp)*8 + gb)*15 + sl)*640;
                if (tid < 160)
                    *(float4*)(&xp_sh[tid*4]) = *(const float4*)(xsrc + tid*4);
            }

            // ---- verify tags, scatter bf16 payload -> h_sh ----
            if (s == 0) {
                const float* h0p = h0 + ((size_t)dir*NB + gb*8)*NH;
                for (int i = tid; i < 2400; i += 256)
                    h_sh16[(i/300)*328 + (i%300)] = bf16r(h0p[i]);
            } else if (tid < 240) {
                const unsigned tg = (unsigned)s & 0xFFFFu;
                bool ok = false;
                while (!ok) {
                    ok = true;
#pragma unroll
                    for (int j = 0; j < 10; ++j) {
                        int i = tid + 256*j;
                        if (i < 2400 && (vb[j] >> 16) != tg) {
                            ok = false;
                            vb[j] = __hip_atomic_load(hsrc + i, __ATOMIC_RELAXED,
                                                      __HIP_MEMORY_SCOPE_AGENT);
                        }
                    }
                }
#pragma unroll
                for (int j = 0; j < 10; ++j) {
                    int i = tid + 256*j;
                    if (i < 2400)
                        h_sh16[(i/300)*328 + (i%300)] = (short)(vb[j] & 0xFFFFu);
                }
            }
            __syncthreads();                               // B1: h ready

            // ---- MFMA: gates = Whh * h (two independent acc chains) ----
            {
                bf16x8 Bf[10];
#pragma unroll
                for (int ks = 0; ks < 10; ++ks)
                    Bf[ks] = *(const bf16x8*)(h_sh16 + lm*328 + ks*32 + lq*8);
                f32x4 acc0, acc1;
#pragma unroll 2
                for (int mt = 0; mt < 2; ++mt) {
                    if (mt < tn) {
#pragma unroll
                        for (int r = 0; r < 4; ++r) { acc0[r] = 0.f; acc1[r] = 0.f; }
#pragma unroll
                        for (int ks = 0; ks < 5; ++ks)
                            acc0 = __builtin_amdgcn_mfma_f32_16x16x32_bf16(
                                       A[mt][ks], Bf[ks], acc0, 0, 0, 0);
#pragma unroll
                        for (int ks = 5; ks < 10; ++ks)
                            acc1 = __builtin_amdgcn_mfma_f32_16x16x32_bf16(
                                       A[mt][ks], Bf[ks], acc1, 0, 0, 0);
                        if (lm < 8) {
#pragma unroll
                            for (int r = 0; r < 4; ++r)
                                gates_sh[((tb+mt)*16 + lq*4 + r)*9 + lm] = acc0[r] + acc1[r];
                        }
                    }
                }
            }
            __syncthreads();                               // B2: gates ready

            // ---- pointwise LSTM cell + tagged publish (publish ASAP) ----
            if (isPW) {
                float G[4];
#pragma unroll
                for (int g = 0; g < 4; ++g)
                    G[g] = xp_sh[bl_p*80 + g*20 + lu_p] + gates_sh[(g*20 + lu_p)*9 + bl_p];
                float ig = 1.f/(1.f+__expf(-G[0]));
                float fg = 1.f/(1.f+__expf(-G[1]));
                float gg = tanh_fast(G[2]);
                float og = 1.f/(1.f+__expf(-G[3]));
                c_reg = fg*c_reg + ig*gg;
                float h = og*tanh_fast(c_reg);
                unsigned hb = (__float_as_uint(h) + 0x8000u) >> 16;
                unsigned pk = (((unsigned)(s+1) & 0xFFFFu) << 16) | hb;
                __hip_atomic_store(
                    &hslot[(((size_t)((s+1)&1)*2 + dir)*NB + gb*8 + bl_p)*NH + u0 + lu_p],
                    pk, __ATOMIC_RELAXED, __HIP_MEMORY_SCOPE_AGENT);
                hloc[bl_p*20 + lu_p] = h;
            }
            __syncthreads();                               // B3: hloc ready

            // ---- emission: per-step fire-and-forget atomics (r1 style) ----
            if (tid < 72) {
                int b = tid/9, k = tid%9;
                float a = 0.f;
#pragma unroll
                for (int u = 0; u < 20; ++u) a += hloc[b*20+u]*wo_sh[k*20+u];
                atomicAdd(&ev[((size_t)t*NB + gb*8 + b)*NK + k], a);
            }
        }

        if (isPW) cbuf[((size_t)dir*NB + gb*8 + bl_p)*NH + u0 + lu_p] = c_reg;

    } else {
        // ================= XPROJ branch (32-step chunk, unchanged) =======
        const int bx = (int)blockIdx.x - nrnn;       // [0, 480)
        const int w  = tid >> 6, L = tid & 63;
        const int lm = L & 15, lq = L >> 4;
        const int xb = bx & 15;                      // 16 m-blocks
        const int yb = (bx >> 4) % 15;               // 15 n-blocks
        const int dir = bx / 240;                    // 2 dirs
        const int m0 = xb*128 + w*32;
        const int n0 = yb*80;
        const int tbase = dir ? (480 - chunk_next*32) : (chunk_next*32);

        const float* arow[2];
#pragma unroll
        for (int mi = 0; mi < 2; ++mi) {
            int m = m0 + mi*16 + lm;
            int b = m >> 5, lt = m & 31;
            arow[mi] = emb + (size_t)tokens[b*512 + tbase + lt] * 300;
        }
        const short* brow[5];
#pragma unroll
        for (int ni = 0; ni < 5; ++ni) {
            int j = n0 + ni*16 + lm;
            brow[ni] = wb16 + ((size_t)dir*1200 + j)*320;
        }

        f32x4 acc[2][5];
#pragma unroll
        for (int mi = 0; mi < 2; ++mi)
#pragma unroll
            for (int ni = 0; ni < 5; ++ni)
#pragma unroll
                for (int r = 0; r < 4; ++r) acc[mi][ni][r] = 0.f;

        const float4 z4 = make_float4(0.f,0.f,0.f,0.f);
        for (int k0 = 0; k0 < 320; k0 += 32) {
            const int kk = k0 + lq*8;
            bf16x8 af[2], bf[5];
#pragma unroll
            for (int mi = 0; mi < 2; ++mi) {
                float4 f1 = (kk   < 300) ? *(const float4*)(arow[mi] + kk)     : z4;
                float4 f2 = (kk+4 < 300) ? *(const float4*)(arow[mi] + kk + 4) : z4;
                af[mi][0]=bf16r(f1.x); af[mi][1]=bf16r(f1.y); af[mi][2]=bf16r(f1.z); af[mi][3]=bf16r(f1.w);
                af[mi][4]=bf16r(f2.x); af[mi][5]=bf16r(f2.y); af[mi][6]=bf16r(f2.z); af[mi][7]=bf16r(f2.w);
            }
#pragma unroll
            for (int ni = 0; ni < 5; ++ni)
                bf[ni] = *(const bf16x8*)(brow[ni] + kk);
#pragma unroll
            for (int mi = 0; mi < 2; ++mi)
#pragma unroll
                for (int ni = 0; ni < 5; ++ni)
                    acc[mi][ni] = __builtin_amdgcn_mfma_f32_16x16x32_bf16(
                                      af[mi], bf[ni], acc[mi][ni], 0, 0, 0);
        }

#pragma unroll
        for (int ni = 0; ni < 5; ++ni) {
            int j = n0 + ni*16 + lm;
            int g = j/300, rr = j%300;
            int slc = rr/20, ul = rr%20;
            float bias = dir ? (bib[j]+bhb[j]) : (bif[j]+bhf[j]);
#pragma unroll
            for (int mi = 0; mi < 2; ++mi) {
#pragma unroll
                for (int r = 0; r < 4; ++r) {
                    int m = m0 + mi*16 + lq*4 + r;
                    int b = m >> 5, lt = m & 31;
                    int sp = dir ? (31 - lt) : lt;
                    size_t idx = ((((size_t)dir*32 + sp)*8 + (b>>3))*15 + slc)*640
                               + (size_t)(b&7)*80 + g*20 + ul;
                    xp_dst[idx] = acc[mi][ni][r] + bias;
                }
            }
        }
    }
}

// =====================================================================
// K3: CRF nll + viterbi — two-wave split scan + parallel backtrack
//   (unchanged — verified, 162us).
// =====================================================================
#define BT_C 14
#define BT_L 37

__global__ __launch_bounds__(128) void k_crf(
    const float* __restrict__ ev, const int* __restrict__ tags,
    const float* __restrict__ start_t, const float* __restrict__ end_t,
    const float* __restrict__ trans, const float* __restrict__ bout,
    float* __restrict__ out)
{
    __shared__ __align__(16) float ex_a[12];
    __shared__ __align__(16) float ex_v[12];
    __shared__ int hist_sh[511*NK];
    __shared__ int fmap[BT_C*NK];
    __shared__ int entry_sh[BT_C];
    __shared__ int last_sh;

    const int b = blockIdx.x, tid = threadIdx.x;
    const int wv = tid >> 6, ln = tid & 63;

    if (wv == 0) {
        float part = 0.f;
        for (int t = ln; t < NT; t += 64) {
            int tc = tags[b*NT + t];
            float e = ev[((size_t)t*NB + b)*NK + tc] + bout[tc];
            float pre = (t == 0) ? start_t[tc] : trans[tags[b*NT + t - 1]*9 + tc];
            part += pre + e;
        }
        if (ln == 63) part += end_t[tags[b*NT + NT - 1]];
#pragma unroll
        for (int off = 32; off > 0; off >>= 1)
            part += __shfl_down(part, off, 64);
        const float num = part;   // lane 0

        if (ln < 9) {
            const int kc = ln;
            float Tc[9];
#pragma unroll
            for (int kp = 0; kp < 9; ++kp) Tc[kp] = __expf(trans[kp*9 + kc]);
            const float bo = bout[kc];
            ex_a[kc] = start_t[kc] + ev[(size_t)b*NK + kc] + bo;
            float etn = ev[((size_t)1*NB + b)*NK + kc] + bo;

            for (int t = 1; t < NT; ++t) {
                float et = etn;
                if (t + 1 < NT) etn = ev[((size_t)(t+1)*NB + b)*NK + kc] + bo;

                float4 s0 = *(const float4*)(&ex_a[0]);
                float4 s1 = *(const float4*)(&ex_a[4]);
                float  a8 = ex_a[8];
                float a0=s0.x,a1=s0.y,a2=s0.z,a3=s0.w,a4=s1.x,a5=s1.y,a6=s1.z,a7=s1.w;

                float M = fmaxf(fmaxf(fmaxf(a0,a1),fmaxf(a2,a3)),
                                fmaxf(fmaxf(a4,a5),fmaxf(a6,a7)));
                M = fmaxf(M, a8);
                float s =        __expf(a0-M)*Tc[0];
                s = fmaf(__expf(a1-M), Tc[1], s);
                s = fmaf(__expf(a2-M), Tc[2], s);
                s = fmaf(__expf(a3-M), Tc[3], s);
                s = fmaf(__expf(a4-M), Tc[4], s);
                s = fmaf(__expf(a5-M), Tc[5], s);
                s = fmaf(__expf(a6-M), Tc[6], s);
                s = fmaf(__expf(a7-M), Tc[7], s);
                s = fmaf(__expf(a8-M), Tc[8], s);
                ex_a[kc] = M + __logf(s) + et;
            }

            if (ln == 0) {
                float M = -1e30f;
#pragma unroll
                for (int k = 0; k < 9; ++k) M = fmaxf(M, ex_a[k] + end_t[k]);
                float ls = 0.f;
#pragma unroll
                for (int k = 0; k < 9; ++k) ls += __expf(ex_a[k] + end_t[k] - M);
                float den = M + __logf(ls);
                atomicAdd(out + NB*NT, den - num);
            }
        }
    } else {
        if (ln < 9) {
            const int kc = ln;
            float Tc[9];
#pragma unroll
            for (int kp = 0; kp < 9; ++kp) Tc[kp] = trans[kp*9 + kc];
            const float bo = bout[kc];
            ex_v[kc] = start_t[kc] + ev[(size_t)b*NK + kc] + bo;
            float etn = ev[((size_t)1*NB + b)*NK + kc] + bo;

            for (int t = 1; t < NT; ++t) {
                float et = etn;
                if (t + 1 < NT) etn = ev[((size_t)(t+1)*NB + b)*NK + kc] + bo;

                float4 s0 = *(const float4*)(&ex_v[0]);
                float4 s1 = *(const float4*)(&ex_v[4]);
                float  a8 = ex_v[8];
                float a0=s0.x,a1=s0.y,a2=s0.z,a3=s0.w,a4=s1.x,a5=s1.y,a6=s1.z,a7=s1.w;

                float bv = a0 + Tc[0]; int arg = 0;
                float v;
                v = a1+Tc[1]; if (v > bv) { bv = v; arg = 1; }
                v = a2+Tc[2]; if (v > bv) { bv = v; arg = 2; }
                v = a3+Tc[3]; if (v > bv) { bv = v; arg = 3; }
                v = a4+Tc[4]; if (v > bv) { bv = v; arg = 4; }
                v = a5+Tc[5]; if (v > bv) { bv = v; arg = 5; }
                v = a6+Tc[6]; if (v > bv) { bv = v; arg = 6; }
                v = a7+Tc[7]; if (v > bv) { bv = v; arg = 7; }
                v = a8+Tc[8]; if (v > bv) { bv = v; arg = 8; }
                hist_sh[(t-1)*NK + kc] = arg;
                ex_v[kc] = bv + et;
            }

            if (ln == 0) {
                float best = -1e30f; int last = 0;
#pragma unroll
                for (int k = 0; k < 9; ++k) {
                    float v = ex_v[k] + end_t[k];
                    if (v > best) { best = v; last = k; }
                }
                last_sh = last;
            }
        }
    }

    __syncthreads();

    if (tid < BT_C*NK) {
        int c = tid / NK, s = tid % NK;
        int lo = c*BT_L, hi = min(511, lo + BT_L);
        int pos = s;
        for (int i = hi - 1; i >= lo; --i) pos = hist_sh[i*NK + pos];
        fmap[c*NK + s] = pos;
    }
    __syncthreads();
    if (tid == 0) {
        int e = last_sh;
        entry_sh[BT_C-1] = e;
        for (int c = BT_C - 2; c >= 0; --c) {
            e = fmap[(c+1)*NK + e];
            entry_sh[c] = e;
        }
    }
    __syncthreads();
    int* pout = (int*)out;
    if (tid < BT_C) {
        int c = tid;
        int lo = c*BT_L, hi = min(511, lo + BT_L);
        int pos = entry_sh[c];
        for (int i = hi - 1; i >= lo; --i) {
            pos = hist_sh[i*NK + pos];
            pout[b*NT + i] = pos;
        }
    }
    if (tid == 0) pout[b*NT + NT - 1] = last_sh;
}

// =====================================================================
extern "C" void kernel_launch(void* const* d_in, const int* in_sizes, int n_in,
                              void* d_out, int out_size, void* d_ws, size_t ws_size,
                              hipStream_t stream)
{
    (void)in_sizes; (void)n_in; (void)ws_size;

    const int*   tokens = (const int*)  d_in[0];
    const int*   tags   = (const int*)  d_in[1];
    const float* emb    = (const float*)d_in[3];
    const float* wihf   = (const float*)d_in[4];
    const float* whhf   = (const float*)d_in[5];
    const float* bihf   = (const float*)d_in[6];
    const float* bhhf   = (const float*)d_in[7];
    const float* wihb   = (const float*)d_in[8];
    const float* whhb   = (const float*)d_in[9];
    const float* bib    = (const float*)d_in[10];
    const float* bhhb   = (const float*)d_in[11];
    const float* h0     = (const float*)d_in[12];
    const float* c0     = (const float*)d_in[13];
    const float* wout   = (const float*)d_in[14];
    const float* bout   = (const float*)d_in[15];
    const float* startt = (const float*)d_in[16];
    const float* endt   = (const float*)d_in[17];
    const float* trans  = (const float*)d_in[18];

    float* ws    = (float*)d_ws;
    short* wb16  = (short*)(ws + WB_OFF);
    short* whh16 = wb16 + 768000;
    float* evp   = ws + E_OFF;
    float* cbuf  = ws + CBUF_OFF;
    unsigned* hslot = (unsigned*)(ws + HSLOT_OFF);
    float* xp    = ws + XP_OFF;          // two XPC32 buffers
    float* out   = (float*)d_out;

    (void)hipMemsetAsync(d_out, 0, (size_t)out_size * sizeof(float), stream);
    (void)hipMemsetAsync(evp, 0, (size_t)E_SZ * sizeof(float), stream);
    // hslot needs NO init: stale tags never falsely match (deterministic
    // replay writes identical bits when tags do coincide).
    (void)hipMemcpyAsync(cbuf, c0, 2ull*NB*NH*sizeof(float), hipMemcpyDeviceToDevice, stream);

    k_wcvt<<<6000, 256, 0, stream>>>(wihf, wihb, whhf, whhb, wb16);

    // chunk 0 xproj alone (480 WGs, do_rnn=0)
    k_fused<<<480, 256, 0, stream>>>(
        tokens, emb, wb16, bihf, bhhf, bib, bhhb,
        xp, 0,
        xp, whh16, h0, hslot, cbuf, evp, wout, 0, 0);

    // fused: rnn(chunk c) + xproj(chunk c+1)
    for (int c = 0; c < 15; ++c) {
        k_fused<<<720, 256, 0, stream>>>(
            tokens, emb, wb16, bihf, bhhf, bib, bhhb,
            xp + (size_t)((c+1)&1)*XPC32_SZ, c+1,
            xp + (size_t)(c&1)*XPC32_SZ, whh16, h0, hslot, cbuf, evp, wout,
            32*c, 1);
    }
    // final chunk: rnn only
    k_fused<<<240, 256, 0, stream>>>(
        tokens, emb, wb16, bihf, bhhf, bib, bhhb,
        xp, 0,
        xp + (size_t)XPC32_SZ, whh16, h0, hslot, cbuf, evp, wout,
        480, 1);

    k_crf<<<64, 128, 0, stream>>>(evp, tags, startt, endt, trans, bout, out);
}

// Round 10
// 1875.587 us; speedup vs baseline: 1.2185x; 1.0725x over previous
//
#include <hip/hip_runtime.h>
#include <math.h>

// Problem constants
#define NV 32000
#define ND 300
#define NH 300
#define NK 9
#define NB 64
#define NT 512

typedef short bf16x8 __attribute__((ext_vector_type(8)));
typedef float f32x4  __attribute__((ext_vector_type(4)));

__device__ inline short bf16r(float x) {
    return (short)((__float_as_uint(x) + 0x8000u) >> 16);
}

__device__ inline float tanh_fast(float x) {
    float e2 = __expf(2.f * x);
    return 1.f - 2.f / (e2 + 1.f);
}

// ---------------- workspace layout (float offsets) ----------------
#define WB_OFF   0ull
#define WB_F     768000ull                // 1,536,000 shorts = 768,000 floats
#define E_OFF    (WB_OFF + WB_F)
#define E_SZ     ((unsigned long long)NT*NB*NK)          // 294,912
#define CBUF_OFF (E_OFF + E_SZ)
#define CBUF_SZ  (2ull*NB*NH)             // 38,400
#define HSLOT_OFF (CBUF_OFF + CBUF_SZ)
#define HSLOT_SZ  (2ull*2*NB*NH)          // 76,800
#define XP_OFF   (HSLOT_OFF + HSLOT_SZ)   // 1,178,112
#define XPC_SZ   (2ull*64*1200*64)        // 9,830,400 floats (64-step chunk)
#define EB_OFF   (XP_OFF + XPC_SZ)        // 11,008,512 (44.03MB boundary)
#define EB_SZ    (32000ull*320/2)         // 5,120,000 floats (bf16 emb)
#define WS_NEED_EB ((EB_OFF + EB_SZ)*4ull) // 64.5MB

// =====================================================================
// K0: convert W_ih AND W_hh (fwd+bwd) to bf16, zero-padded K 300->320.
// =====================================================================
__global__ __launch_bounds__(256) void k_wcvt(
    const float* __restrict__ wihf, const float* __restrict__ wihb,
    const float* __restrict__ whhf, const float* __restrict__ whhb,
    short* __restrict__ dst)
{
    int i = blockIdx.x*256 + threadIdx.x;          // over 4*1200*320
    if (i >= 1536000) return;
    int d  = i / 384000;
    int r2 = i % 384000;
    int j  = r2 / 320, k = r2 % 320;
    const float* src = (d == 0) ? wihf : (d == 1) ? wihb : (d == 2) ? whhf : whhb;
    float v = (k < 300) ? src[(size_t)j*300 + k] : 0.f;
    dst[i] = bf16r(v);
}

// =====================================================================
// K0b: convert embedding f32[32000][300] -> bf16[32000][320] (zero-pad).
//   Removes 16 VALU cvts + half the A-bytes per k-iter from k_xproj.
// =====================================================================
__global__ __launch_bounds__(256) void k_ecvt(
    const float* __restrict__ emb, short* __restrict__ dst)
{
    int i = blockIdx.x*256 + threadIdx.x;          // over 32000*320
    if (i >= 32000*320) return;
    int row = i / 320, col = i % 320;
    float v = (col < 300) ? emb[(size_t)row*300 + col] : 0.f;
    dst[i] = bf16r(v);
}

// =====================================================================
// K1: xproj GEMM (r1-verified), 64-step chunk, optional bf16-emb A path.
// =====================================================================
__global__ __launch_bounds__(256) void k_xproj(
    const int* __restrict__ tokens, const float* __restrict__ emb,
    const short* __restrict__ eb16, int use_eb,
    const short* __restrict__ wb16,
    const float* __restrict__ bif, const float* __restrict__ bhf,
    const float* __restrict__ bib, const float* __restrict__ bhb,
    float* __restrict__ xpc, int chunk)
{
    const int tid = threadIdx.x;
    const int w  = tid >> 6, L = tid & 63;
    const int lm = L & 15, lq = L >> 4;
    const int dir = blockIdx.z;
    const int m0 = blockIdx.x*128 + w*32;
    const int n0 = blockIdx.y*80;
    const int tbase = dir ? (448 - chunk*64) : (chunk*64);

    int tok[2];
#pragma unroll
    for (int mi = 0; mi < 2; ++mi) {
        int m = m0 + mi*16 + lm;
        int b = m >> 6, lt = m & 63;
        tok[mi] = tokens[b*512 + tbase + lt];
    }
    const short* brow[5];
#pragma unroll
    for (int ni = 0; ni < 5; ++ni) {
        int j = n0 + ni*16 + lm;
        brow[ni] = wb16 + ((size_t)dir*1200 + j)*320;
    }

    f32x4 acc[2][5];
#pragma unroll
    for (int mi = 0; mi < 2; ++mi)
#pragma unroll
        for (int ni = 0; ni < 5; ++ni)
#pragma unroll
            for (int r = 0; r < 4; ++r) acc[mi][ni][r] = 0.f;

    if (use_eb) {
        const short* arow[2];
#pragma unroll
        for (int mi = 0; mi < 2; ++mi) arow[mi] = eb16 + (size_t)tok[mi]*320;
        for (int k0 = 0; k0 < 320; k0 += 32) {
            const int kk = k0 + lq*8;
            bf16x8 af[2], bf[5];
#pragma unroll
            for (int mi = 0; mi < 2; ++mi)
                af[mi] = *(const bf16x8*)(arow[mi] + kk);
#pragma unroll
            for (int ni = 0; ni < 5; ++ni)
                bf[ni] = *(const bf16x8*)(brow[ni] + kk);
#pragma unroll
            for (int mi = 0; mi < 2; ++mi)
#pragma unroll
                for (int ni = 0; ni < 5; ++ni)
                    acc[mi][ni] = __builtin_amdgcn_mfma_f32_16x16x32_bf16(
                                      af[mi], bf[ni], acc[mi][ni], 0, 0, 0);
        }
    } else {
        const float* arow[2];
#pragma unroll
        for (int mi = 0; mi < 2; ++mi) arow[mi] = emb + (size_t)tok[mi]*300;
        const float4 z4 = make_float4(0.f,0.f,0.f,0.f);
        for (int k0 = 0; k0 < 320; k0 += 32) {
            const int kk = k0 + lq*8;
            bf16x8 af[2], bf[5];
#pragma unroll
            for (int mi = 0; mi < 2; ++mi) {
                float4 f1 = (kk   < 300) ? *(const float4*)(arow[mi] + kk)     : z4;
                float4 f2 = (kk+4 < 300) ? *(const float4*)(arow[mi] + kk + 4) : z4;
                af[mi][0]=bf16r(f1.x); af[mi][1]=bf16r(f1.y); af[mi][2]=bf16r(f1.z); af[mi][3]=bf16r(f1.w);
                af[mi][4]=bf16r(f2.x); af[mi][5]=bf16r(f2.y); af[mi][6]=bf16r(f2.z); af[mi][7]=bf16r(f2.w);
            }
#pragma unroll
            for (int ni = 0; ni < 5; ++ni)
                bf[ni] = *(const bf16x8*)(brow[ni] + kk);
#pragma unroll
            for (int mi = 0; mi < 2; ++mi)
#pragma unroll
                for (int ni = 0; ni < 5; ++ni)
                    acc[mi][ni] = __builtin_amdgcn_mfma_f32_16x16x32_bf16(
                                      af[mi], bf[ni], acc[mi][ni], 0, 0, 0);
        }
    }

#pragma unroll
    for (int ni = 0; ni < 5; ++ni) {
        int j = n0 + ni*16 + lm;
        int g = j/300, rr = j%300;
        int slc = rr/20, ul = rr%20;
        float bias = dir ? (bib[j]+bhb[j]) : (bif[j]+bhf[j]);
#pragma unroll
        for (int mi = 0; mi < 2; ++mi) {
#pragma unroll
            for (int r = 0; r < 4; ++r) {
                int m = m0 + mi*16 + lq*4 + r;
                int b = m >> 6, lt = m & 63;
                int sp = dir ? (63 - lt) : lt;
                size_t idx = ((((size_t)dir*64 + sp)*8 + (b>>3))*15 + slc)*640
                           + (size_t)(b&7)*80 + g*20 + ul;
                xpc[idx] = acc[mi][ni][r] + bias;
            }
        }
    }
}

// =====================================================================
// K2: persistent bidirectional LSTM recurrence — EXACT round-1 body
//   (measured 2.47us/step, the best rnn rate on the ledger):
//   __syncthreads barriers, single-chain MFMA acc, fast tanh,
//   publish-before-hloc, per-step fire-and-forget emission atomics.
//   Runs ALONE on the machine (240 WGs, no co-resident xproj).
// =====================================================================
__global__ __launch_bounds__(256) void k_rnn(
    const float* __restrict__ xpc,
    const short* __restrict__ whh16,     // wb16 + 768000: [2][1200][320]
    const float* __restrict__ h0,
    unsigned* hslot, float* __restrict__ cbuf,
    float* __restrict__ ev, const float* __restrict__ wout,
    int s_begin, int s_count)
{
    __shared__ __align__(16) short h_sh16[16*328];   // [b16][k328] bf16
    __shared__ __align__(16) float xp_sh[640];
    __shared__ __align__(16) float gates_sh[80*9];   // [r80][b8] pad 9
    __shared__ __align__(16) float wo_sh[180];
    __shared__ __align__(16) float hloc[160];

    const int tid = threadIdx.x;
    const int wv  = tid >> 6, L = tid & 63;
    const int lm  = L & 15, lq = L >> 4;
    const int dir = blockIdx.x / 120;
    const int rem = blockIdx.x % 120;
    const int sl  = rem / 8;
    const int gb  = rem % 8;
    const int u0  = sl * 20;

    const int tb = (wv == 0) ? 0 : (wv + 1);
    const int tn = (wv == 0) ? 2 : 1;

    bf16x8 A[2][10];
#pragma unroll 2
    for (int mt = 0; mt < 2; ++mt) {
        if (mt < tn) {
            int r = (tb + mt)*16 + lm;
            int grow = (r/20)*300 + u0 + (r%20);
            const short* wr = whh16 + ((size_t)dir*1200 + grow)*320;
#pragma unroll
            for (int ks = 0; ks < 10; ++ks)
                A[mt][ks] = *(const bf16x8*)(wr + ks*32 + lq*8);
        }
    }
    if (tid < 180) wo_sh[tid] = wout[(tid/20)*600 + dir*300 + u0 + (tid%20)];

    for (int i = tid; i < 16*328; i += 256) h_sh16[i] = 0;

    const bool isPW = (tid < 160);
    const int bl_p = tid/20, lu_p = tid%20;
    float c_reg = 0.f;
    if (isPW) c_reg = cbuf[((size_t)dir*NB + gb*8 + bl_p)*NH + u0 + lu_p];

    __syncthreads();

    for (int s = s_begin; s < s_begin + s_count; ++s) {
        const int t = dir ? (511 - s) : s;
        const int sp = s - s_begin;

        // ---- speculative tagged loads of h^(s) (one L3 trip) ----
        unsigned vb[10];
        unsigned* hsrc = hslot + (((size_t)(s & 1)*2 + dir)*NB + gb*8)*NH;
        if (s > 0 && tid < 240) {
#pragma unroll
            for (int j = 0; j < 10; ++j) {
                int i = tid + 256*j;
                if (i < 2400)
                    vb[j] = __hip_atomic_load(hsrc + i, __ATOMIC_RELAXED,
                                              __HIP_MEMORY_SCOPE_AGENT);
            }
        }

        // ---- stage xp (h-independent; overlaps loads) ----
        {
            const float* xsrc = xpc + ((((size_t)dir*64 + sp)*8 + gb)*15 + sl)*640;
            if (tid < 160) *(float4*)(&xp_sh[tid*4]) = *(const float4*)(xsrc + tid*4);
        }

        // ---- verify tags, scatter bf16 payload -> h_sh ----
        if (s == 0) {
            const float* h0p = h0 + ((size_t)dir*NB + gb*8)*NH;
            for (int i = tid; i < 2400; i += 256)
                h_sh16[(i/300)*328 + (i%300)] = bf16r(h0p[i]);
        } else if (tid < 240) {
            const unsigned tg = (unsigned)s & 0xFFFFu;
            bool ok = false;
            while (!ok) {
                ok = true;
#pragma unroll
                for (int j = 0; j < 10; ++j) {
                    int i = tid + 256*j;
                    if (i < 2400 && (vb[j] >> 16) != tg) {
                        ok = false;
                        vb[j] = __hip_atomic_load(hsrc + i, __ATOMIC_RELAXED,
                                                  __HIP_MEMORY_SCOPE_AGENT);
                    }
                }
            }
#pragma unroll
            for (int j = 0; j < 10; ++j) {
                int i = tid + 256*j;
                if (i < 2400)
                    h_sh16[(i/300)*328 + (i%300)] = (short)(vb[j] & 0xFFFFu);
            }
        }
        __syncthreads();                                   // B1: h ready

        // ---- MFMA: gates = Whh * h ----
        {
            bf16x8 Bf[10];
#pragma unroll
            for (int ks = 0; ks < 10; ++ks)
                Bf[ks] = *(const bf16x8*)(h_sh16 + lm*328 + ks*32 + lq*8);
            f32x4 acc[2];
#pragma unroll 2
            for (int mt = 0; mt < 2; ++mt) {
                if (mt < tn) {
#pragma unroll
                    for (int r = 0; r < 4; ++r) acc[mt][r] = 0.f;
#pragma unroll
                    for (int ks = 0; ks < 10; ++ks)
                        acc[mt] = __builtin_amdgcn_mfma_f32_16x16x32_bf16(
                                      A[mt][ks], Bf[ks], acc[mt], 0, 0, 0);
                    if (lm < 8) {
#pragma unroll
                        for (int r = 0; r < 4; ++r)
                            gates_sh[((tb+mt)*16 + lq*4 + r)*9 + lm] = acc[mt][r];
                    }
                }
            }
        }
        __syncthreads();                                   // B2: gates ready

        // ---- pointwise LSTM cell + tagged publish (publish ASAP) ----
        if (isPW) {
            float G[4];
#pragma unroll
            for (int g = 0; g < 4; ++g)
                G[g] = xp_sh[bl_p*80 + g*20 + lu_p] + gates_sh[(g*20 + lu_p)*9 + bl_p];
            float ig = 1.f/(1.f+__expf(-G[0]));
            float fg = 1.f/(1.f+__expf(-G[1]));
            float gg = tanh_fast(G[2]);
            float og = 1.f/(1.f+__expf(-G[3]));
            c_reg = fg*c_reg + ig*gg;
            float h = og*tanh_fast(c_reg);
            unsigned hb = (__float_as_uint(h) + 0x8000u) >> 16;
            unsigned pk = (((unsigned)(s+1) & 0xFFFFu) << 16) | hb;
            __hip_atomic_store(
                &hslot[(((size_t)((s+1)&1)*2 + dir)*NB + gb*8 + bl_p)*NH + u0 + lu_p],
                pk, __ATOMIC_RELAXED, __HIP_MEMORY_SCOPE_AGENT);
            hloc[bl_p*20 + lu_p] = h;
        }
        __syncthreads();                                   // B3: hloc ready

        // ---- fused emission contribution (off critical path) ----
        if (tid < 72) {
            int b = tid/9, k = tid%9;
            float a = 0.f;
#pragma unroll
            for (int u = 0; u < 20; ++u) a += hloc[b*20+u]*wo_sh[k*20+u];
            atomicAdd(&ev[((size_t)t*NB + gb*8 + b)*NK + k], a);
        }
    }

    if (isPW) cbuf[((size_t)dir*NB + gb*8 + bl_p)*NH + u0 + lu_p] = c_reg;
}

// =====================================================================
// K3: CRF nll + viterbi — two-wave split scan + parallel backtrack
//   (unchanged — verified, 162us).
// =====================================================================
#define BT_C 14
#define BT_L 37

__global__ __launch_bounds__(128) void k_crf(
    const float* __restrict__ ev, const int* __restrict__ tags,
    const float* __restrict__ start_t, const float* __restrict__ end_t,
    const float* __restrict__ trans, const float* __restrict__ bout,
    float* __restrict__ out)
{
    __shared__ __align__(16) float ex_a[12];
    __shared__ __align__(16) float ex_v[12];
    __shared__ int hist_sh[511*NK];
    __shared__ int fmap[BT_C*NK];
    __shared__ int entry_sh[BT_C];
    __shared__ int last_sh;

    const int b = blockIdx.x, tid = threadIdx.x;
    const int wv = tid >> 6, ln = tid & 63;

    if (wv == 0) {
        float part = 0.f;
        for (int t = ln; t < NT; t += 64) {
            int tc = tags[b*NT + t];
            float e = ev[((size_t)t*NB + b)*NK + tc] + bout[tc];
            float pre = (t == 0) ? start_t[tc] : trans[tags[b*NT + t - 1]*9 + tc];
            part += pre + e;
        }
        if (ln == 63) part += end_t[tags[b*NT + NT - 1]];
#pragma unroll
        for (int off = 32; off > 0; off >>= 1)
            part += __shfl_down(part, off, 64);
        const float num = part;   // lane 0

        if (ln < 9) {
            const int kc = ln;
            float Tc[9];
#pragma unroll
            for (int kp = 0; kp < 9; ++kp) Tc[kp] = __expf(trans[kp*9 + kc]);
            const float bo = bout[kc];
            ex_a[kc] = start_t[kc] + ev[(size_t)b*NK + kc] + bo;
            float etn = ev[((size_t)1*NB + b)*NK + kc] + bo;

            for (int t = 1; t < NT; ++t) {
                float et = etn;
                if (t + 1 < NT) etn = ev[((size_t)(t+1)*NB + b)*NK + kc] + bo;

                float4 s0 = *(const float4*)(&ex_a[0]);
                float4 s1 = *(const float4*)(&ex_a[4]);
                float  a8 = ex_a[8];
                float a0=s0.x,a1=s0.y,a2=s0.z,a3=s0.w,a4=s1.x,a5=s1.y,a6=s1.z,a7=s1.w;

                float M = fmaxf(fmaxf(fmaxf(a0,a1),fmaxf(a2,a3)),
                                fmaxf(fmaxf(a4,a5),fmaxf(a6,a7)));
                M = fmaxf(M, a8);
                float s =        __expf(a0-M)*Tc[0];
                s = fmaf(__expf(a1-M), Tc[1], s);
                s = fmaf(__expf(a2-M), Tc[2], s);
                s = fmaf(__expf(a3-M), Tc[3], s);
                s = fmaf(__expf(a4-M), Tc[4], s);
                s = fmaf(__expf(a5-M), Tc[5], s);
                s = fmaf(__expf(a6-M), Tc[6], s);
                s = fmaf(__expf(a7-M), Tc[7], s);
                s = fmaf(__expf(a8-M), Tc[8], s);
                ex_a[kc] = M + __logf(s) + et;
            }

            if (ln == 0) {
                float M = -1e30f;
#pragma unroll
                for (int k = 0; k < 9; ++k) M = fmaxf(M, ex_a[k] + end_t[k]);
                float ls = 0.f;
#pragma unroll
                for (int k = 0; k < 9; ++k) ls += __expf(ex_a[k] + end_t[k] - M);
                float den = M + __logf(ls);
                atomicAdd(out + NB*NT, den - num);
            }
        }
    } else {
        if (ln < 9) {
            const int kc = ln;
            float Tc[9];
#pragma unroll
            for (int kp = 0; kp < 9; ++kp) Tc[kp] = trans[kp*9 + kc];
            const float bo = bout[kc];
            ex_v[kc] = start_t[kc] + ev[(size_t)b*NK + kc] + bo;
            float etn = ev[((size_t)1*NB + b)*NK + kc] + bo;

            for (int t = 1; t < NT; ++t) {
                float et = etn;
                if (t + 1 < NT) etn = ev[((size_t)(t+1)*NB + b)*NK + kc] + bo;

                float4 s0 = *(const float4*)(&ex_v[0]);
                float4 s1 = *(const float4*)(&ex_v[4]);
                float  a8 = ex_v[8];
                float a0=s0.x,a1=s0.y,a2=s0.z,a3=s0.w,a4=s1.x,a5=s1.y,a6=s1.z,a7=s1.w;

                float bv = a0 + Tc[0]; int arg = 0;
                float v;
                v = a1+Tc[1]; if (v > bv) { bv = v; arg = 1; }
                v = a2+Tc[2]; if (v > bv) { bv = v; arg = 2; }
                v = a3+Tc[3]; if (v > bv) { bv = v; arg = 3; }
                v = a4+Tc[4]; if (v > bv) { bv = v; arg = 4; }
                v = a5+Tc[5]; if (v > bv) { bv = v; arg = 5; }
                v = a6+Tc[6]; if (v > bv) { bv = v; arg = 6; }
                v = a7+Tc[7]; if (v > bv) { bv = v; arg = 7; }
                v = a8+Tc[8]; if (v > bv) { bv = v; arg = 8; }
                hist_sh[(t-1)*NK + kc] = arg;
                ex_v[kc] = bv + et;
            }

            if (ln == 0) {
                float best = -1e30f; int last = 0;
#pragma unroll
                for (int k = 0; k < 9; ++k) {
                    float v = ex_v[k] + end_t[k];
                    if (v > best) { best = v; last = k; }
                }
                last_sh = last;
            }
        }
    }

    __syncthreads();

    if (tid < BT_C*NK) {
        int c = tid / NK, s = tid % NK;
        int lo = c*BT_L, hi = min(511, lo + BT_L);
        int pos = s;
        for (int i = hi - 1; i >= lo; --i) pos = hist_sh[i*NK + pos];
        fmap[c*NK + s] = pos;
    }
    __syncthreads();
    if (tid == 0) {
        int e = last_sh;
        entry_sh[BT_C-1] = e;
        for (int c = BT_C - 2; c >= 0; --c) {
            e = fmap[(c+1)*NK + e];
            entry_sh[c] = e;
        }
    }
    __syncthreads();
    int* pout = (int*)out;
    if (tid < BT_C) {
        int c = tid;
        int lo = c*BT_L, hi = min(511, lo + BT_L);
        int pos = entry_sh[c];
        for (int i = hi - 1; i >= lo; --i) {
            pos = hist_sh[i*NK + pos];
            pout[b*NT + i] = pos;
        }
    }
    if (tid == 0) pout[b*NT + NT - 1] = last_sh;
}

// =====================================================================
extern "C" void kernel_launch(void* const* d_in, const int* in_sizes, int n_in,
                              void* d_out, int out_size, void* d_ws, size_t ws_size,
                              hipStream_t stream)
{
    (void)in_sizes; (void)n_in;

    const int*   tokens = (const int*)  d_in[0];
    const int*   tags   = (const int*)  d_in[1];
    const float* emb    = (const float*)d_in[3];
    const float* wihf   = (const float*)d_in[4];
    const float* whhf   = (const float*)d_in[5];
    const float* bihf   = (const float*)d_in[6];
    const float* bhhf   = (const float*)d_in[7];
    const float* wihb   = (const float*)d_in[8];
    const float* whhb   = (const float*)d_in[9];
    const float* bib    = (const float*)d_in[10];
    const float* bhhb   = (const float*)d_in[11];
    const float* h0     = (const float*)d_in[12];
    const float* c0     = (const float*)d_in[13];
    const float* wout   = (const float*)d_in[14];
    const float* bout   = (const float*)d_in[15];
    const float* startt = (const float*)d_in[16];
    const float* endt   = (const float*)d_in[17];
    const float* trans  = (const float*)d_in[18];

    float* ws    = (float*)d_ws;
    short* wb16  = (short*)(ws + WB_OFF);
    short* whh16 = wb16 + 768000;
    float* evp   = ws + E_OFF;
    float* cbuf  = ws + CBUF_OFF;
    unsigned* hslot = (unsigned*)(ws + HSLOT_OFF);
    float* xp    = ws + XP_OFF;          // one 64-step chunk buffer
    short* eb16  = (short*)(ws + EB_OFF);
    float* out   = (float*)d_out;

    const int use_eb = (ws_size >= WS_NEED_EB) ? 1 : 0;

    (void)hipMemsetAsync(d_out, 0, (size_t)out_size * sizeof(float), stream);
    (void)hipMemsetAsync(evp, 0, (size_t)E_SZ * sizeof(float), stream);
    // hslot needs NO init: stale tags never falsely match (deterministic
    // replay writes identical bits when tags do coincide).
    (void)hipMemcpyAsync(cbuf, c0, 2ull*NB*NH*sizeof(float), hipMemcpyDeviceToDevice, stream);

    k_wcvt<<<6000, 256, 0, stream>>>(wihf, wihb, whhf, whhb, wb16);
    if (use_eb)
        k_ecvt<<<40000, 256, 0, stream>>>(emb, eb16);

    for (int c = 0; c < 8; ++c) {
        k_xproj<<<dim3(32, 15, 2), 256, 0, stream>>>(
            tokens, emb, eb16, use_eb, wb16, bihf, bhhf, bib, bhhb, xp, c);
        k_rnn<<<240, 256, 0, stream>>>(
            xp, whh16, h0, hslot, cbuf, evp, wout, c*64, 64);
    }
    k_crf<<<64, 128, 0, stream>>>(evp, tags, startt, endt, trans, bout, out);
}

// Round 12
// 1788.780 us; speedup vs baseline: 1.2776x; 1.0485x over previous
//
#include <hip/hip_runtime.h>
#include <math.h>

// Problem constants
#define NV 32000
#define ND 300
#define NH 300
#define NK 9
#define NB 64
#define NT 512

typedef short bf16x8 __attribute__((ext_vector_type(8)));
typedef float f32x4  __attribute__((ext_vector_type(4)));

__device__ inline short bf16r(float x) {
    return (short)((__float_as_uint(x) + 0x8000u) >> 16);
}

__device__ inline float tanh_fast(float x) {
    float e2 = __expf(2.f * x);
    return 1.f - 2.f / (e2 + 1.f);
}

// ---------------- workspace layout (float offsets) ----------------
#define WB_OFF   0ull
#define WB_F     768000ull                // 1,536,000 shorts = 768,000 floats
#define E_OFF    (WB_OFF + WB_F)
#define E_SZ     ((unsigned long long)NT*NB*NK)          // 294,912
#define CBUF_OFF (E_OFF + E_SZ)
#define CBUF_SZ  (2ull*NB*NH)             // 38,400
#define HSLOT_OFF (CBUF_OFF + CBUF_SZ)
#define HSLOT_SZ  (2ull*2*NB*NH)          // 76,800
#define XP_OFF   (HSLOT_OFF + HSLOT_SZ)   // 1,178,112
#define XPC_SZ   (2ull*64*1200*64)        // 9,830,400 floats (64-step chunk)
#define EB_OFF   (XP_OFF + XPC_SZ)        // 11,008,512 (44.03MB boundary)
#define EB_SZ    (32000ull*320/2)         // 5,120,000 floats (bf16 emb)
#define WS_NEED_EB ((EB_OFF + EB_SZ)*4ull) // 64.5MB

// =====================================================================
// K0: convert W_ih AND W_hh (fwd+bwd) to bf16, zero-padded K 300->320.
// =====================================================================
__global__ __launch_bounds__(256) void k_wcvt(
    const float* __restrict__ wihf, const float* __restrict__ wihb,
    const float* __restrict__ whhf, const float* __restrict__ whhb,
    short* __restrict__ dst)
{
    int i = blockIdx.x*256 + threadIdx.x;          // over 4*1200*320
    if (i >= 1536000) return;
    int d  = i / 384000;
    int r2 = i % 384000;
    int j  = r2 / 320, k = r2 % 320;
    const float* src = (d == 0) ? wihf : (d == 1) ? wihb : (d == 2) ? whhf : whhb;
    float v = (k < 300) ? src[(size_t)j*300 + k] : 0.f;
    dst[i] = bf16r(v);
}

// =====================================================================
// K0b: convert embedding f32[32000][300] -> bf16[32000][320] (zero-pad).
// =====================================================================
__global__ __launch_bounds__(256) void k_ecvt(
    const float* __restrict__ emb, short* __restrict__ dst)
{
    int i = blockIdx.x*256 + threadIdx.x;          // over 32000*320
    if (i >= 32000*320) return;
    int row = i / 320, col = i % 320;
    float v = (col < 300) ? emb[(size_t)row*300 + col] : 0.f;
    dst[i] = bf16r(v);
}

// =====================================================================
// K1: xproj GEMM (r1-verified), 64-step chunk, optional bf16-emb A path.
// =====================================================================
__global__ __launch_bounds__(256) void k_xproj(
    const int* __restrict__ tokens, const float* __restrict__ emb,
    const short* __restrict__ eb16, int use_eb,
    const short* __restrict__ wb16,
    const float* __restrict__ bif, const float* __restrict__ bhf,
    const float* __restrict__ bib, const float* __restrict__ bhb,
    float* __restrict__ xpc, int chunk)
{
    const int tid = threadIdx.x;
    const int w  = tid >> 6, L = tid & 63;
    const int lm = L & 15, lq = L >> 4;
    const int dir = blockIdx.z;
    const int m0 = blockIdx.x*128 + w*32;
    const int n0 = blockIdx.y*80;
    const int tbase = dir ? (448 - chunk*64) : (chunk*64);

    int tok[2];
#pragma unroll
    for (int mi = 0; mi < 2; ++mi) {
        int m = m0 + mi*16 + lm;
        int b = m >> 6, lt = m & 63;
        tok[mi] = tokens[b*512 + tbase + lt];
    }
    const short* brow[5];
#pragma unroll
    for (int ni = 0; ni < 5; ++ni) {
        int j = n0 + ni*16 + lm;
        brow[ni] = wb16 + ((size_t)dir*1200 + j)*320;
    }

    f32x4 acc[2][5];
#pragma unroll
    for (int mi = 0; mi < 2; ++mi)
#pragma unroll
        for (int ni = 0; ni < 5; ++ni)
#pragma unroll
            for (int r = 0; r < 4; ++r) acc[mi][ni][r] = 0.f;

    if (use_eb) {
        const short* arow[2];
#pragma unroll
        for (int mi = 0; mi < 2; ++mi) arow[mi] = eb16 + (size_t)tok[mi]*320;
        for (int k0 = 0; k0 < 320; k0 += 32) {
            const int kk = k0 + lq*8;
            bf16x8 af[2], bf[5];
#pragma unroll
            for (int mi = 0; mi < 2; ++mi)
                af[mi] = *(const bf16x8*)(arow[mi] + kk);
#pragma unroll
            for (int ni = 0; ni < 5; ++ni)
                bf[ni] = *(const bf16x8*)(brow[ni] + kk);
#pragma unroll
            for (int mi = 0; mi < 2; ++mi)
#pragma unroll
                for (int ni = 0; ni < 5; ++ni)
                    acc[mi][ni] = __builtin_amdgcn_mfma_f32_16x16x32_bf16(
                                      af[mi], bf[ni], acc[mi][ni], 0, 0, 0);
        }
    } else {
        const float* arow[2];
#pragma unroll
        for (int mi = 0; mi < 2; ++mi) arow[mi] = emb + (size_t)tok[mi]*300;
        const float4 z4 = make_float4(0.f,0.f,0.f,0.f);
        for (int k0 = 0; k0 < 320; k0 += 32) {
            const int kk = k0 + lq*8;
            bf16x8 af[2], bf[5];
#pragma unroll
            for (int mi = 0; mi < 2; ++mi) {
                float4 f1 = (kk   < 300) ? *(const float4*)(arow[mi] + kk)     : z4;
                float4 f2 = (kk+4 < 300) ? *(const float4*)(arow[mi] + kk + 4) : z4;
                af[mi][0]=bf16r(f1.x); af[mi][1]=bf16r(f1.y); af[mi][2]=bf16r(f1.z); af[mi][3]=bf16r(f1.w);
                af[mi][4]=bf16r(f2.x); af[mi][5]=bf16r(f2.y); af[mi][6]=bf16r(f2.z); af[mi][7]=bf16r(f2.w);
            }
#pragma unroll
            for (int ni = 0; ni < 5; ++ni)
                bf[ni] = *(const bf16x8*)(brow[ni] + kk);
#pragma unroll
            for (int mi = 0; mi < 2; ++mi)
#pragma unroll
                for (int ni = 0; ni < 5; ++ni)
                    acc[mi][ni] = __builtin_amdgcn_mfma_f32_16x16x32_bf16(
                                      af[mi], bf[ni], acc[mi][ni], 0, 0, 0);
        }
    }

#pragma unroll
    for (int ni = 0; ni < 5; ++ni) {
        int j = n0 + ni*16 + lm;
        int g = j/300, rr = j%300;
        int slc = rr/20, ul = rr%20;
        float bias = dir ? (bib[j]+bhb[j]) : (bif[j]+bhf[j]);
#pragma unroll
        for (int mi = 0; mi < 2; ++mi) {
#pragma unroll
            for (int r = 0; r < 4; ++r) {
                int m = m0 + mi*16 + lq*4 + r;
                int b = m >> 6, lt = m & 63;
                int sp = dir ? (63 - lt) : lt;
                size_t idx = ((((size_t)dir*64 + sp)*8 + (b>>3))*15 + slc)*640
                           + (size_t)(b&7)*80 + g*20 + ul;
                xpc[idx] = acc[mi][ni][r] + bias;
            }
        }
    }
}

// =====================================================================
// K2: persistent bidirectional LSTM recurrence — EXACT round-1 body
//   (best measured 2.47us/step). UNCHANGED from round 10.
// =====================================================================
__global__ __launch_bounds__(256) void k_rnn(
    const float* __restrict__ xpc,
    const short* __restrict__ whh16,     // wb16 + 768000: [2][1200][320]
    const float* __restrict__ h0,
    unsigned* hslot, float* __restrict__ cbuf,
    float* __restrict__ ev, const float* __restrict__ wout,
    int s_begin, int s_count)
{
    __shared__ __align__(16) short h_sh16[16*328];   // [b16][k328] bf16
    __shared__ __align__(16) float xp_sh[640];
    __shared__ __align__(16) float gates_sh[80*9];   // [r80][b8] pad 9
    __shared__ __align__(16) float wo_sh[180];
    __shared__ __align__(16) float hloc[160];

    const int tid = threadIdx.x;
    const int wv  = tid >> 6, L = tid & 63;
    const int lm  = L & 15, lq = L >> 4;
    const int dir = blockIdx.x / 120;
    const int rem = blockIdx.x % 120;
    const int sl  = rem / 8;
    const int gb  = rem % 8;
    const int u0  = sl * 20;

    const int tb = (wv == 0) ? 0 : (wv + 1);
    const int tn = (wv == 0) ? 2 : 1;

    bf16x8 A[2][10];
#pragma unroll 2
    for (int mt = 0; mt < 2; ++mt) {
        if (mt < tn) {
            int r = (tb + mt)*16 + lm;
            int grow = (r/20)*300 + u0 + (r%20);
            const short* wr = whh16 + ((size_t)dir*1200 + grow)*320;
#pragma unroll
            for (int ks = 0; ks < 10; ++ks)
                A[mt][ks] = *(const bf16x8*)(wr + ks*32 + lq*8);
        }
    }
    if (tid < 180) wo_sh[tid] = wout[(tid/20)*600 + dir*300 + u0 + (tid%20)];

    for (int i = tid; i < 16*328; i += 256) h_sh16[i] = 0;

    const bool isPW = (tid < 160);
    const int bl_p = tid/20, lu_p = tid%20;
    float c_reg = 0.f;
    if (isPW) c_reg = cbuf[((size_t)dir*NB + gb*8 + bl_p)*NH + u0 + lu_p];

    __syncthreads();

    for (int s = s_begin; s < s_begin + s_count; ++s) {
        const int t = dir ? (511 - s) : s;
        const int sp = s - s_begin;

        // ---- speculative tagged loads of h^(s) (one L3 trip) ----
        unsigned vb[10];
        unsigned* hsrc = hslot + (((size_t)(s & 1)*2 + dir)*NB + gb*8)*NH;
        if (s > 0 && tid < 240) {
#pragma unroll
            for (int j = 0; j < 10; ++j) {
                int i = tid + 256*j;
                if (i < 2400)
                    vb[j] = __hip_atomic_load(hsrc + i, __ATOMIC_RELAXED,
                                              __HIP_MEMORY_SCOPE_AGENT);
            }
        }

        // ---- stage xp (h-independent; overlaps loads) ----
        {
            const float* xsrc = xpc + ((((size_t)dir*64 + sp)*8 + gb)*15 + sl)*640;
            if (tid < 160) *(float4*)(&xp_sh[tid*4]) = *(const float4*)(xsrc + tid*4);
        }

        // ---- verify tags, scatter bf16 payload -> h_sh ----
        if (s == 0) {
            const float* h0p = h0 + ((size_t)dir*NB + gb*8)*NH;
            for (int i = tid; i < 2400; i += 256)
                h_sh16[(i/300)*328 + (i%300)] = bf16r(h0p[i]);
        } else if (tid < 240) {
            const unsigned tg = (unsigned)s & 0xFFFFu;
            bool ok = false;
            while (!ok) {
                ok = true;
#pragma unroll
                for (int j = 0; j < 10; ++j) {
                    int i = tid + 256*j;
                    if (i < 2400 && (vb[j] >> 16) != tg) {
                        ok = false;
                        vb[j] = __hip_atomic_load(hsrc + i, __ATOMIC_RELAXED,
                                                  __HIP_MEMORY_SCOPE_AGENT);
                    }
                }
            }
#pragma unroll
            for (int j = 0; j < 10; ++j) {
                int i = tid + 256*j;
                if (i < 2400)
                    h_sh16[(i/300)*328 + (i%300)] = (short)(vb[j] & 0xFFFFu);
            }
        }
        __syncthreads();                                   // B1: h ready

        // ---- MFMA: gates = Whh * h ----
        {
            bf16x8 Bf[10];
#pragma unroll
            for (int ks = 0; ks < 10; ++ks)
                Bf[ks] = *(const bf16x8*)(h_sh16 + lm*328 + ks*32 + lq*8);
            f32x4 acc[2];
#pragma unroll 2
            for (int mt = 0; mt < 2; ++mt) {
                if (mt < tn) {
#pragma unroll
                    for (int r = 0; r < 4; ++r) acc[mt][r] = 0.f;
#pragma unroll
                    for (int ks = 0; ks < 10; ++ks)
                        acc[mt] = __builtin_amdgcn_mfma_f32_16x16x32_bf16(
                                      A[mt][ks], Bf[ks], acc[mt], 0, 0, 0);
                    if (lm < 8) {
#pragma unroll
                        for (int r = 0; r < 4; ++r)
                            gates_sh[((tb+mt)*16 + lq*4 + r)*9 + lm] = acc[mt][r];
                    }
                }
            }
        }
        __syncthreads();                                   // B2: gates ready

        // ---- pointwise LSTM cell + tagged publish (publish ASAP) ----
        if (isPW) {
            float G[4];
#pragma unroll
            for (int g = 0; g < 4; ++g)
                G[g] = xp_sh[bl_p*80 + g*20 + lu_p] + gates_sh[(g*20 + lu_p)*9 + bl_p];
            float ig = 1.f/(1.f+__expf(-G[0]));
            float fg = 1.f/(1.f+__expf(-G[1]));
            float gg = tanh_fast(G[2]);
            float og = 1.f/(1.f+__expf(-G[3]));
            c_reg = fg*c_reg + ig*gg;
            float h = og*tanh_fast(c_reg);
            unsigned hb = (__float_as_uint(h) + 0x8000u) >> 16;
            unsigned pk = (((unsigned)(s+1) & 0xFFFFu) << 16) | hb;
            __hip_atomic_store(
                &hslot[(((size_t)((s+1)&1)*2 + dir)*NB + gb*8 + bl_p)*NH + u0 + lu_p],
                pk, __ATOMIC_RELAXED, __HIP_MEMORY_SCOPE_AGENT);
            hloc[bl_p*20 + lu_p] = h;
        }
        __syncthreads();                                   // B3: hloc ready

        // ---- fused emission contribution (off critical path) ----
        if (tid < 72) {
            int b = tid/9, k = tid%9;
            float a = 0.f;
#pragma unroll
            for (int u = 0; u < 20; ++u) a += hloc[b*20+u]*wo_sh[k*20+u];
            atomicAdd(&ev[((size_t)t*NB + gb*8 + b)*NK + k], a);
        }
    }

    if (isPW) cbuf[((size_t)dir*NB + gb*8 + bl_p)*NH + u0 + lu_p] = c_reg;
}

// =====================================================================
// K3: CRF — chunk-parallel semiring scan. REQUIRES 256 THREADS
//   (r11 bug: launched with 128 -> waves 2/3 never ran, half the
//   numerator missing, Mlse[7]/Mvit[7] uninitialized. Fixed launcher.)
//   P1: per (semiring, chunk), 9 lanes propagate basis vectors in
//       registers -> 9x9 chunk transfer matrices.
//   P2: two threads compose 8 matrices -> denominator / entry states.
//   P3: chunks re-scan viterbi in parallel -> backpointer table.
//   P4: verified 3-phase parallel backtrack. Serial depth: 511 -> 64.
// =====================================================================
#define BT_C 14
#define BT_L 37
#define CC 8          // chunks
#define CL 64         // chunk length (last = 63)

__global__ __launch_bounds__(256) void k_crf(
    const float* __restrict__ ev, const int* __restrict__ tags,
    const float* __restrict__ start_t, const float* __restrict__ end_t,
    const float* __restrict__ trans, const float* __restrict__ bout,
    float* __restrict__ out)
{
    __shared__ int hist_sh[511*NK];
    __shared__ float Mlse[CC*81];
    __shared__ float Mvit[CC*81];
    __shared__ float entry_v[CC*9];
    __shared__ __align__(16) float ex3[CC*12];
    __shared__ float num_sh[256];
    __shared__ int fmap[BT_C*NK];
    __shared__ int entry_sh[BT_C];
    __shared__ int last_sh;

    const int b = blockIdx.x, tid = threadIdx.x;
    const int wv = tid >> 6;

    // ---------- phase A: numerator partials (all 256 threads) ----------
    {
        float part = 0.f;
        for (int t = tid; t < NT; t += 256) {
            int tc = tags[b*NT + t];
            float e = ev[((size_t)t*NB + b)*NK + tc] + bout[tc];
            float pre = (t == 0) ? start_t[tc] : trans[tags[b*NT + t - 1]*9 + tc];
            part += pre + e;
            if (t == NT - 1) part += end_t[tc];
        }
        num_sh[tid] = part;
    }

    // ---------- phase 1: chunk transfer matrices ----------
    // wave0: LSE chunks 0-6 | wave1: vit chunks 0-6 | wave2: LSE c7 | wave3: vit c7
    {
        int c = -1, j0 = 0, sr = 0;
        if (wv == 0)      { if (tid < 63)        { c = tid/9;        j0 = tid%9;        sr = 0; } }
        else if (wv == 1) { if (tid-64 < 63)     { c = (tid-64)/9;   j0 = (tid-64)%9;   sr = 1; } }
        else if (wv == 2) { if (tid-128 < 9)     { c = 7;            j0 = tid-128;      sr = 0; } }
        else              { if (tid-192 < 9)     { c = 7;            j0 = tid-192;      sr = 1; } }

        if (c >= 0 && sr == 0) {
            // LSE semiring, basis row j0
            float Te[9][9];
#pragma unroll
            for (int i = 0; i < 9; ++i)
#pragma unroll
                for (int j = 0; j < 9; ++j) Te[i][j] = __expf(trans[i*9 + j]);
            float bo[9];
#pragma unroll
            for (int j = 0; j < 9; ++j) bo[j] = bout[j];
            float a[9];
#pragma unroll
            for (int j = 0; j < 9; ++j) a[j] = (j == j0) ? 0.f : -1e30f;
            const int t0 = 1 + c*CL;
            float etn[9];
#pragma unroll
            for (int j = 0; j < 9; ++j)
                etn[j] = ev[((size_t)t0*NB + b)*NK + j] + bo[j];
            for (int k = 0; k < CL; ++k) {
                int t = t0 + k;
                if (t >= NT) break;                 // uniform (only c=7 wave)
                float et[9];
#pragma unroll
                for (int j = 0; j < 9; ++j) et[j] = etn[j];
                if (t + 1 < NT) {
#pragma unroll
                    for (int j = 0; j < 9; ++j)
                        etn[j] = ev[((size_t)(t+1)*NB + b)*NK + j] + bo[j];
                }
                float M = a[0];
#pragma unroll
                for (int i = 1; i < 9; ++i) M = fmaxf(M, a[i]);
                float p[9];
#pragma unroll
                for (int i = 0; i < 9; ++i) p[i] = __expf(a[i] - M);
#pragma unroll
                for (int j = 0; j < 9; ++j) {
                    float s = p[0]*Te[0][j];
#pragma unroll
                    for (int i = 1; i < 9; ++i) s = fmaf(p[i], Te[i][j], s);
                    a[j] = M + __logf(s) + et[j];
                }
            }
#pragma unroll
            for (int j = 0; j < 9; ++j) Mlse[c*81 + j0*9 + j] = a[j];
        } else if (c >= 0) {
            // max-plus semiring (values only; args in phase 3)
            float Tv[9][9];
#pragma unroll
            for (int i = 0; i < 9; ++i)
#pragma unroll
                for (int j = 0; j < 9; ++j) Tv[i][j] = trans[i*9 + j];
            float bo[9];
#pragma unroll
            for (int j = 0; j < 9; ++j) bo[j] = bout[j];
            float a[9];
#pragma unroll
            for (int j = 0; j < 9; ++j) a[j] = (j == j0) ? 0.f : -1e30f;
            const int t0 = 1 + c*CL;
            float etn[9];
#pragma unroll
            for (int j = 0; j < 9; ++j)
                etn[j] = ev[((size_t)t0*NB + b)*NK + j] + bo[j];
            for (int k = 0; k < CL; ++k) {
                int t = t0 + k;
                if (t >= NT) break;
                float et[9];
#pragma unroll
                for (int j = 0; j < 9; ++j) et[j] = etn[j];
                if (t + 1 < NT) {
#pragma unroll
                    for (int j = 0; j < 9; ++j)
                        etn[j] = ev[((size_t)(t+1)*NB + b)*NK + j] + bo[j];
                }
                float an[9];
#pragma unroll
                for (int j = 0; j < 9; ++j) {
                    float bv = a[0] + Tv[0][j];
#pragma unroll
                    for (int i = 1; i < 9; ++i) bv = fmaxf(bv, a[i] + Tv[i][j]);
                    an[j] = bv + et[j];
                }
#pragma unroll
                for (int j = 0; j < 9; ++j) a[j] = an[j];
            }
#pragma unroll
            for (int j = 0; j < 9; ++j) Mvit[c*81 + j0*9 + j] = a[j];
        }
    }
    __syncthreads();

    // ---------- phase 2: compose (two independent threads) ----------
    if (tid == 0) {
        // numerator reduce
        float num = 0.f;
        for (int i = 0; i < 256; ++i) num += num_sh[i];
        // LSE compose
        float al[9];
#pragma unroll
        for (int j = 0; j < 9; ++j)
            al[j] = start_t[j] + ev[(size_t)b*NK + j] + bout[j];
        for (int c = 0; c < CC; ++c) {
            float an[9];
#pragma unroll
            for (int j = 0; j < 9; ++j) {
                float m = al[0] + Mlse[c*81 + 0*9 + j];
#pragma unroll
                for (int i = 1; i < 9; ++i)
                    m = fmaxf(m, al[i] + Mlse[c*81 + i*9 + j]);
                float s = 0.f;
#pragma unroll
                for (int i = 0; i < 9; ++i)
                    s += __expf(al[i] + Mlse[c*81 + i*9 + j] - m);
                an[j] = m + __logf(s);
            }
#pragma unroll
            for (int j = 0; j < 9; ++j) al[j] = an[j];
        }
        float M = al[0] + end_t[0];
#pragma unroll
        for (int j = 1; j < 9; ++j) M = fmaxf(M, al[j] + end_t[j]);
        float ls = 0.f;
#pragma unroll
        for (int j = 0; j < 9; ++j) ls += __expf(al[j] + end_t[j] - M);
        float den = M + __logf(ls);
        atomicAdd(out + NB*NT, den - num);
    }
    if (tid == 64) {
        // max-plus compose -> entry states + final argmax
        float av[9];
#pragma unroll
        for (int j = 0; j < 9; ++j)
            av[j] = start_t[j] + ev[(size_t)b*NK + j] + bout[j];
        for (int c = 0; c < CC; ++c) {
#pragma unroll
            for (int j = 0; j < 9; ++j) entry_v[c*9 + j] = av[j];
            float an[9];
#pragma unroll
            for (int j = 0; j < 9; ++j) {
                float bv = av[0] + Mvit[c*81 + 0*9 + j];
#pragma unroll
                for (int i = 1; i < 9; ++i)
                    bv = fmaxf(bv, av[i] + Mvit[c*81 + i*9 + j]);
                an[j] = bv;
            }
#pragma unroll
            for (int j = 0; j < 9; ++j) av[j] = an[j];
        }
        float best = av[0] + end_t[0]; int last = 0;
#pragma unroll
        for (int j = 1; j < 9; ++j) {
            float v = av[j] + end_t[j];
            if (v > best) { best = v; last = j; }
        }
        last_sh = last;
    }
    __syncthreads();

    // ---------- phase 3: parallel viterbi history regeneration ----------
    // wave0: chunks 0-6 (9-lane groups); wave1: chunk 7
    {
        int c = -1, j3 = 0;
        if (wv == 0)      { if (tid < 63)    { c = tid/9;  j3 = tid%9;  } }
        else if (wv == 1) { if (tid-64 < 9)  { c = 7;      j3 = tid-64; } }
        if (c >= 0) {
            float Tc[9];
#pragma unroll
            for (int i = 0; i < 9; ++i) Tc[i] = trans[i*9 + j3];
            const float bo3 = bout[j3];
            ex3[c*12 + j3] = entry_v[c*9 + j3];
            const int t0 = 1 + c*CL;
            float etn = ev[((size_t)t0*NB + b)*NK + j3] + bo3;
            for (int k = 0; k < CL; ++k) {
                int t = t0 + k;
                if (t >= NT) break;                 // uniform (only c=7 wave)
                float et = etn;
                if (t + 1 < NT)
                    etn = ev[((size_t)(t+1)*NB + b)*NK + j3] + bo3;

                float4 s0 = *(const float4*)(&ex3[c*12]);
                float4 s1 = *(const float4*)(&ex3[c*12 + 4]);
                float  a8 = ex3[c*12 + 8];
                float a0=s0.x,a1=s0.y,a2=s0.z,a3=s0.w,a4=s1.x,a5=s1.y,a6=s1.z,a7=s1.w;

                float bv = a0 + Tc[0]; int arg = 0;
                float v;
                v = a1+Tc[1]; if (v > bv) { bv = v; arg = 1; }
                v = a2+Tc[2]; if (v > bv) { bv = v; arg = 2; }
                v = a3+Tc[3]; if (v > bv) { bv = v; arg = 3; }
                v = a4+Tc[4]; if (v > bv) { bv = v; arg = 4; }
                v = a5+Tc[5]; if (v > bv) { bv = v; arg = 5; }
                v = a6+Tc[6]; if (v > bv) { bv = v; arg = 6; }
                v = a7+Tc[7]; if (v > bv) { bv = v; arg = 7; }
                v = a8+Tc[8]; if (v > bv) { bv = v; arg = 8; }
                hist_sh[(t-1)*NK + j3] = arg;
                ex3[c*12 + j3] = bv + et;
            }
        }
    }
    __syncthreads();

    // ---------- phase 4: parallel backtrack (verified) ----------
    if (tid < BT_C*NK) {
        int c = tid / NK, s = tid % NK;
        int lo = c*BT_L, hi = min(511, lo + BT_L);
        int pos = s;
        for (int i = hi - 1; i >= lo; --i) pos = hist_sh[i*NK + pos];
        fmap[c*NK + s] = pos;
    }
    __syncthreads();
    if (tid == 0) {
        int e = last_sh;
        entry_sh[BT_C-1] = e;
        for (int c = BT_C - 2; c >= 0; --c) {
            e = fmap[(c+1)*NK + e];
            entry_sh[c] = e;
        }
    }
    __syncthreads();
    int* pout = (int*)out;
    if (tid < BT_C) {
        int c = tid;
        int lo = c*BT_L, hi = min(511, lo + BT_L);
        int pos = entry_sh[c];
        for (int i = hi - 1; i >= lo; --i) {
            pos = hist_sh[i*NK + pos];
            pout[b*NT + i] = pos;
        }
    }
    if (tid == 0) pout[b*NT + NT - 1] = last_sh;
}

// =====================================================================
extern "C" void kernel_launch(void* const* d_in, const int* in_sizes, int n_in,
                              void* d_out, int out_size, void* d_ws, size_t ws_size,
                              hipStream_t stream)
{
    (void)in_sizes; (void)n_in;

    const int*   tokens = (const int*)  d_in[0];
    const int*   tags   = (const int*)  d_in[1];
    const float* emb    = (const float*)d_in[3];
    const float* wihf   = (const float*)d_in[4];
    const float* whhf   = (const float*)d_in[5];
    const float* bihf   = (const float*)d_in[6];
    const float* bhhf   = (const float*)d_in[7];
    const float* wihb   = (const float*)d_in[8];
    const float* whhb   = (const float*)d_in[9];
    const float* bib    = (const float*)d_in[10];
    const float* bhhb   = (const float*)d_in[11];
    const float* h0     = (const float*)d_in[12];
    const float* c0     = (const float*)d_in[13];
    const float* wout   = (const float*)d_in[14];
    const float* bout   = (const float*)d_in[15];
    const float* startt = (const float*)d_in[16];
    const float* endt   = (const float*)d_in[17];
    const float* trans  = (const float*)d_in[18];

    float* ws    = (float*)d_ws;
    short* wb16  = (short*)(ws + WB_OFF);
    short* whh16 = wb16 + 768000;
    float* evp   = ws + E_OFF;
    float* cbuf  = ws + CBUF_OFF;
    unsigned* hslot = (unsigned*)(ws + HSLOT_OFF);
    float* xp    = ws + XP_OFF;          // one 64-step chunk buffer
    short* eb16  = (short*)(ws + EB_OFF);
    float* out   = (float*)d_out;

    const int use_eb = (ws_size >= WS_NEED_EB) ? 1 : 0;

    (void)hipMemsetAsync(d_out, 0, (size_t)out_size * sizeof(float), stream);
    (void)hipMemsetAsync(evp, 0, (size_t)E_SZ * sizeof(float), stream);
    // hslot needs NO init: stale tags never falsely match (deterministic
    // replay writes identical bits when tags do coincide).
    (void)hipMemcpyAsync(cbuf, c0, 2ull*NB*NH*sizeof(float), hipMemcpyDeviceToDevice, stream);

    k_wcvt<<<6000, 256, 0, stream>>>(wihf, wihb, whhf, whhb, wb16);
    if (use_eb)
        k_ecvt<<<40000, 256, 0, stream>>>(emb, eb16);

    for (int c = 0; c < 8; ++c) {
        k_xproj<<<dim3(32, 15, 2), 256, 0, stream>>>(
            tokens, emb, eb16, use_eb, wb16, bihf, bhhf, bib, bhhb, xp, c);
        k_rnn<<<240, 256, 0, stream>>>(
            xp, whh16, h0, hslot, cbuf, evp, wout, c*64, 64);
    }
    k_crf<<<64, 256, 0, stream>>>(evp, tags, startt, endt, trans, bout, out);
}